// Round 3
// baseline (256.596 us; speedup 1.0000x reference)
//
#include <hip/hip_runtime.h>

typedef __attribute__((ext_vector_type(8))) short s16x8;
typedef __attribute__((ext_vector_type(4))) short s16x4;
typedef __attribute__((ext_vector_type(4))) float f32x4;
typedef __attribute__((ext_vector_type(4))) unsigned u32x4;

namespace {
constexpr int kCS = 256, kDH = 64, kDS = 128, kBH = 512;
constexpr float kAlpha = 0.5f;

// LDS byte offsets (total 30 KB -> 5 blocks/CU, 20 waves/CU)
constexpr int OFF_AC   = 0;                  // ac: 256 f32
constexpr int OFF_ENEG = 1024;               // eneg: 256 f32
constexpr int OFF_B    = 2048;               // Bhi [32][128] s16 (8KB); aliased by C fp32 bounce (16KB) and HThi half
constexpr int OFF_BLO  = OFF_B + 8192;       // Blo / HTlo
constexpr int OFF_XT   = OFF_B + 16384;      // XThi [64][32] s16 (4KB)
constexpr int OFF_XTLO = OFF_XT + 4096;      // XTlo
constexpr int OFF_S    = OFF_XTLO + 4096;    // S~hi per-wave [16][32] s16, 4 waves (4KB); cumsum partials early
constexpr int LDS_BYTES = OFF_S + 4096;      // 30720
}

union F4 { float4 v; float f[4]; };

// packed f32x2 -> bf16x2 (RNE), 1 VALU inst
__device__ __forceinline__ unsigned cvt_pk_bf16(float a, float b) {
  unsigned r;
  asm("v_cvt_pk_bf16_f32 %0, %1, %2" : "=v"(r) : "v"(a), "v"(b));
  return r;
}

__device__ __forceinline__ unsigned short bf16_1(float x) {
  return (unsigned short)cvt_pk_bf16(x, x);
}

// hi = bf16(a),bf16(b); lo = bf16 of residuals. All static accesses.
__device__ __forceinline__ void split2(float a, float b, unsigned& h, unsigned& l) {
  h = cvt_pk_bf16(a, b);
  l = cvt_pk_bf16(a - __uint_as_float(h << 16), b - __uint_as_float(h & 0xFFFF0000u));
}

__device__ __forceinline__ void split8v(float4 a, float4 b, s16x8& hi, s16x8& lo) {
  unsigned h0, h1, h2, h3, l0, l1, l2, l3;
  split2(a.x, a.y, h0, l0);
  split2(a.z, a.w, h1, l1);
  split2(b.x, b.y, h2, l2);
  split2(b.z, b.w, h3, l3);
  u32x4 H = {h0, h1, h2, h3}, L = {l0, l1, l2, l3};
  hi = __builtin_bit_cast(s16x8, H);
  lo = __builtin_bit_cast(s16x8, L);
}

__device__ __forceinline__ void split8s(float x0, float x1, float x2, float x3,
                                        float x4, float x5, float x6, float x7,
                                        s16x8& hi, s16x8& lo) {
  unsigned h0, h1, h2, h3, l0, l1, l2, l3;
  split2(x0, x1, h0, l0);
  split2(x2, x3, h1, l1);
  split2(x4, x5, h2, l2);
  split2(x6, x7, h3, l3);
  u32x4 H = {h0, h1, h2, h3}, L = {l0, l1, l2, l3};
  hi = __builtin_bit_cast(s16x8, H);
  lo = __builtin_bit_cast(s16x8, L);
}

// LDS ping-pong scan for hend_kernel (unchanged path)
__device__ __forceinline__ void cumsum256(const float* __restrict__ Ab, float* ac, int tid) {
  ac[tid] = Ab[tid];
  __syncthreads();
  for (int off = 1; off < kCS; off <<= 1) {
    float v = ac[tid];
    if (tid >= off) v += ac[tid - off];
    __syncthreads();
    ac[tid] = v;
    __syncthreads();
  }
}

// barrier that waits only this wave's LDS ops -> prefetch vmcnt stays in flight
__device__ __forceinline__ void lds_barrier() {
  asm volatile("s_waitcnt lgkmcnt(0)" ::: "memory");
  __builtin_amdgcn_s_barrier();
  __builtin_amdgcn_sched_barrier(0);
}

// Y[i,d] = (1-a)*sum_{j<=i} exp(ac_i-ac_j)*CB[i,j]*X[j,d] + a*exp(ac_i)*(C·h_prev)[i,d]
__global__ __launch_bounds__(256, 5) void y_mfma_kernel(
    const float* __restrict__ Xg, const float* __restrict__ Ag,
    const float* __restrict__ Bg, const float* __restrict__ Cg,
    const float* __restrict__ Hg, float* __restrict__ Yg) {
  __shared__ __align__(16) char smem[LDS_BYTES];
  float* ac   = (float*)(smem + OFF_AC);
  float* eneg = (float*)(smem + OFF_ENEG);
  short* Bhi  = (short*)(smem + OFF_B);
  short* Blo  = (short*)(smem + OFF_BLO);
  short* XThi = (short*)(smem + OFF_XT);
  short* XTlo = (short*)(smem + OFF_XTLO);
  short* Sall = (short*)(smem + OFF_S);
  float* Cb   = (float*)(smem + OFF_B);   // fp32 bounce, aliases Bhi+Blo (16KB)
  short* HThi = Bhi;                      // h_prev^T half-planes alias B planes
  short* HTlo = Blo;

  const int bidx = blockIdx.x;
  const int it = 3 - (bidx >> 9);   // heavy tiles dispatched first
  const int bh = bidx & 511;
  const int tid = threadIdx.x;
  const int lane = tid & 63;
  const int w = tid >> 6;
  const int fr = lane & 15;   // fragment free-index (A row / B col / D col)
  const int fg = lane >> 4;   // fragment k-group

  const float* Xb = Xg + (size_t)bh * kCS * kDH;
  const float* Ab = Ag + (size_t)bh * kCS;
  const float* Bb = Bg + (size_t)bh * kCS * kDS;
  const float* Cg_b = Cg + (size_t)bh * kCS * kDS;
  const float* Hb = Hg + (size_t)bh * kDS * kDH;
  float* Yb = Yg + (size_t)bh * kCS * kDH;

  // ---- cumsum via wave shuffle scan
  {
    float v = Ab[tid];
#pragma unroll
    for (int off = 1; off < 64; off <<= 1) {
      float t = __shfl_up(v, off);
      if (lane >= off) v += t;
    }
    float* wsum = (float*)(smem + OFF_S);
    if (lane == 63) wsum[w] = v;
    __syncthreads();
    float base = 0.f;
#pragma unroll
    for (int k = 0; k < 4; ++k)
      if (k < w) base += wsum[k];
    const float a = v + base;
    ac[tid] = a;
    eneg[tid] = __expf(-a);
    __syncthreads();
  }

  const int i0 = it * 64;
  float eaci[4];
#pragma unroll
  for (int r = 0; r < 4; ++r) eaci[r] = __expf(ac[i0 + w * 16 + fg * 4 + r]);

  // ---- issue jt=0 prefetch early: latency hides under the C-bounce phase
  const int prow = tid >> 4;
  const int pg = tid & 15;
  float4 pb0, pb1, pb2, pb3;
  float px0, px1, px2, px3, px4, px5, px6, px7;
  {
    pb0 = *(const float4*)&Bb[(size_t)prow * kDS + pg * 8];
    pb1 = *(const float4*)&Bb[(size_t)prow * kDS + pg * 8 + 4];
    pb2 = *(const float4*)&Bb[(size_t)(16 + prow) * kDS + pg * 8];
    pb3 = *(const float4*)&Bb[(size_t)(16 + prow) * kDS + pg * 8 + 4];
    const float* xp = &Xb[(size_t)(w * 8) * kDH + lane];
    px0 = xp[0 * kDH]; px1 = xp[1 * kDH]; px2 = xp[2 * kDH]; px3 = xp[3 * kDH];
    px4 = xp[4 * kDH]; px5 = xp[5 * kDH]; px6 = xp[6 * kDH]; px7 = xp[7 * kDH];
  }

  // ---- C bounce in two 32-row halves: global (coalesced) -> LDS fp32 (16B-block XOR swizzle)
  s16x8 chi[4], clo[4];
#pragma unroll
  for (int m = 0; m < 2; ++m) {
#pragma unroll
    for (int k = 0; k < 4; ++k) {
      int fid = k * 256 + tid;
      int r = fid >> 5, c = fid & 31;
      *(float4*)&Cb[r * 128 + ((c ^ (r & 7)) << 2)] =
          *(const float4*)&Cg_b[(size_t)(i0 + m * 32 + r) * kDS + c * 4];
    }
    __syncthreads();
    if ((w >> 1) == m) {
      const int lrow = (w & 1) * 16 + fr;
      const float* crow = &Cb[lrow * 128];
      const int r7 = lrow & 7;
#pragma unroll
      for (int kc = 0; kc < 4; ++kc) {
        const int c0 = kc * 8 + fg * 2;
        F4 u0, u1;
        u0.v = *(const float4*)&crow[(c0 ^ r7) << 2];
        u1.v = *(const float4*)&crow[((c0 + 1) ^ r7) << 2];
        split8v(u0.v, u1.v, chi[kc], clo[kc]);
      }
    }
    __syncthreads();
  }

  f32x4 yacc[4];
#pragma unroll
  for (int n = 0; n < 4; ++n)
#pragma unroll
    for (int r = 0; r < 4; ++r) yacc[n][r] = 0.f;

  short* Sp = Sall + w * 512;  // per-wave S~ plane [16][32]

  const int jt_n = 2 * it + 2;

  for (int jt = 0; jt < jt_n; ++jt) {
    // ---- split+write current tile from named prefetch regs
    {
      s16x8 h8, l8;
      split8v(pb0, pb1, h8, l8);
      int col = (pg ^ (prow & 7)) * 8;
      *(s16x8*)&Bhi[prow * 128 + col] = h8;
      *(s16x8*)&Blo[prow * 128 + col] = l8;
      const int row1 = 16 + prow;
      split8v(pb2, pb3, h8, l8);
      col = (pg ^ (row1 & 7)) * 8;
      *(s16x8*)&Bhi[row1 * 128 + col] = h8;
      *(s16x8*)&Blo[row1 * 128 + col] = l8;
    }
    {
      s16x8 h8, l8;
      split8s(px0, px1, px2, px3, px4, px5, px6, px7, h8, l8);
      const int d = lane;
      const int off = d * 32 + ((w ^ ((d >> 2) & 3)) << 3);
      *(s16x8*)&XThi[off] = h8;
      *(s16x8*)&XTlo[off] = l8;
    }
    // ---- issue next tile's loads; they stay in flight across both lds_barriers
    if (jt + 1 < jt_n) {
      const int j0n = (jt + 1) * 32;
      pb0 = *(const float4*)&Bb[(size_t)(j0n + prow) * kDS + pg * 8];
      pb1 = *(const float4*)&Bb[(size_t)(j0n + prow) * kDS + pg * 8 + 4];
      pb2 = *(const float4*)&Bb[(size_t)(j0n + 16 + prow) * kDS + pg * 8];
      pb3 = *(const float4*)&Bb[(size_t)(j0n + 16 + prow) * kDS + pg * 8 + 4];
      const float* xp = &Xb[(size_t)(j0n + w * 8) * kDH + lane];
      px0 = xp[0 * kDH]; px1 = xp[1 * kDH]; px2 = xp[2 * kDH]; px3 = xp[3 * kDH];
      px4 = xp[4 * kDH]; px5 = xp[5 * kDH]; px6 = xp[6 * kDH]; px7 = xp[7 * kDH];
    }
    lds_barrier();

    const int j0 = jt * 32;
    // ---- S = C·B^T  (split: Chi·Bhi + Chi·Blo + Clo·Bhi)
    f32x4 s[2];
#pragma unroll
    for (int n = 0; n < 2; ++n) {
#pragma unroll
      for (int r = 0; r < 4; ++r) s[n][r] = 0.f;
      const int jrow = n * 16 + fr;
      const short* bph = &Bhi[jrow * 128];
      const short* bpl = &Blo[jrow * 128];
#pragma unroll
      for (int kc = 0; kc < 4; ++kc) {
        const int phys = ((4 * kc + fg) ^ (jrow & 7)) * 8;
        s16x8 b8 = *(const s16x8*)&bph[phys];
        s16x8 l8 = *(const s16x8*)&bpl[phys];
        s[n] = __builtin_amdgcn_mfma_f32_16x16x32_bf16(chi[kc], b8, s[n], 0, 0, 0);
        s[n] = __builtin_amdgcn_mfma_f32_16x16x32_bf16(chi[kc], l8, s[n], 0, 0, 0);
        s[n] = __builtin_amdgcn_mfma_f32_16x16x32_bf16(clo[kc], b8, s[n], 0, 0, 0);
      }
    }
    // ---- mask + decay, write S~ (bf16 hi) to per-wave plane (block-XOR swizzle)
#pragma unroll
    for (int n = 0; n < 2; ++n) {
      const int jg = j0 + n * 16 + fr;
      const float enj = eneg[jg];
#pragma unroll
      for (int r = 0; r < 4; ++r) {
        const int iwl = fg * 4 + r;
        const int ig = i0 + w * 16 + iwl;
        float sv = s[n][r] * eaci[r] * enj;
        sv = (jg <= ig) ? sv : 0.f;
        Sp[iwl * 32 + (((n * 2 + (fr >> 3)) ^ fg) << 3) + (fr & 7)] = (short)bf16_1(sv);
      }
    }
    // ---- PV: Y += S~ · X   (S~hi·Xhi + S~hi·Xlo)
    {
      s16x8 sa = *(const s16x8*)&Sp[fr * 32 + ((fg ^ (fr >> 2)) << 3)];
#pragma unroll
      for (int n = 0; n < 4; ++n) {
        const int drow = n * 16 + fr;
        const int pxo = (fg ^ ((drow >> 2) & 3)) << 3;
        s16x8 xh = *(const s16x8*)&XThi[drow * 32 + pxo];
        s16x8 xl = *(const s16x8*)&XTlo[drow * 32 + pxo];
        yacc[n] = __builtin_amdgcn_mfma_f32_16x16x32_bf16(sa, xh, yacc[n], 0, 0, 0);
        yacc[n] = __builtin_amdgcn_mfma_f32_16x16x32_bf16(sa, xl, yacc[n], 0, 0, 0);
      }
    }
    lds_barrier();
  }

  // ---- Yh = C · h_prev in two s-halves (HT half-plane aliases B planes, 16KB)
  f32x4 yh[4];
#pragma unroll
  for (int n = 0; n < 4; ++n)
#pragma unroll
    for (int r = 0; r < 4; ++r) yh[n][r] = 0.f;

#pragma unroll
  for (int m = 0; m < 2; ++m) {
    // stage h_prev^T half: h[64s][64d] -> HT[d][s_local] hi/lo
    {
      const int dd = tid & 15, tt = tid >> 4;
      F4 hr[4];
#pragma unroll
      for (int r = 0; r < 4; ++r)
        hr[r].v = *(const float4*)&Hb[(size_t)(m * 64 + tt * 4 + r) * kDH + dd * 4];
#pragma unroll
      for (int c = 0; c < 4; ++c) {
        const int d = dd * 4 + c;
        unsigned h0, h1, l0, l1;
        split2(hr[0].f[c], hr[1].f[c], h0, l0);
        split2(hr[2].f[c], hr[3].f[c], h1, l1);
        const int off = d * 64 + (((tt >> 1) ^ (d & 7)) << 3) + ((tt & 1) << 2);
        ((unsigned*)&HThi[off])[0] = h0;
        ((unsigned*)&HThi[off])[1] = h1;
        ((unsigned*)&HTlo[off])[0] = l0;
        ((unsigned*)&HTlo[off])[1] = l1;
      }
    }
    __syncthreads();
#pragma unroll
    for (int kcl = 0; kcl < 2; ++kcl) {
      const int kc = m * 2 + kcl;
#pragma unroll
      for (int n = 0; n < 4; ++n) {
        const int drow = n * 16 + fr;
        const int phys = ((4 * kcl + fg) ^ (drow & 7)) * 8;
        s16x8 hh = *(const s16x8*)&HThi[drow * 64 + phys];
        s16x8 hl = *(const s16x8*)&HTlo[drow * 64 + phys];
        yh[n] = __builtin_amdgcn_mfma_f32_16x16x32_bf16(chi[kc], hh, yh[n], 0, 0, 0);
        yh[n] = __builtin_amdgcn_mfma_f32_16x16x32_bf16(chi[kc], hl, yh[n], 0, 0, 0);
        yh[n] = __builtin_amdgcn_mfma_f32_16x16x32_bf16(clo[kc], hh, yh[n], 0, 0, 0);
      }
    }
    if (m == 0) __syncthreads();  // before half-1 staging overwrites HT
  }

  // ---- epilogue: Y = (1-a)*Y_intra + a*exp(ac_i)*Yh
#pragma unroll
  for (int n = 0; n < 4; ++n) {
#pragma unroll
    for (int r = 0; r < 4; ++r) {
      const int ig = i0 + w * 16 + fg * 4 + r;
      const int d = n * 16 + fr;
      Yb[(size_t)ig * kDH + d] = (1.f - kAlpha) * yacc[n][r] + (kAlpha * eaci[r]) * yh[n][r];
    }
  }
}

// h_end[s,d] = alpha*decay_total*h_prev[s,d] + (1-alpha)*sum_t B[t,s]*w_t*X[t,d]
__global__ __launch_bounds__(256, 2) void hend_kernel(
    const float* __restrict__ Xg, const float* __restrict__ Ag,
    const float* __restrict__ Bg, const float* __restrict__ Hg,
    float* __restrict__ hend, float* __restrict__ dtot) {
  const int bh = blockIdx.x;
  const int tid = threadIdx.x;
  const float* Xb = Xg + (size_t)bh * kCS * kDH;
  const float* Ab = Ag + (size_t)bh * kCS;
  const float* Bb = Bg + (size_t)bh * kCS * kDS;
  const float* Hb = Hg + (size_t)bh * kDS * kDH;
  float* Ob = hend + (size_t)bh * kDS * kDH;

  __shared__ float ac[kCS];
  __shared__ float wsh[32];
  __shared__ float xs[32][kDH];
  __shared__ float bs[32][kDS];

  cumsum256(Ab, ac, tid);
  const float alast = ac[kCS - 1];
  if (tid == 0) dtot[bh] = __expf(alast);

  const int dcol = tid & 15;
  const int srow = tid >> 4;
  float4 acc[8];
#pragma unroll
  for (int m = 0; m < 8; ++m) acc[m] = make_float4(0.f, 0.f, 0.f, 0.f);

  for (int t0 = 0; t0 < kCS; t0 += 32) {
    __syncthreads();
    if (tid < 32) wsh[tid] = __expf(alast - ac[t0 + tid]);
    __syncthreads();
#pragma unroll
    for (int k = 0; k < 2; ++k) {
      int fid = k * 256 + tid;
      int r = fid >> 4, c = fid & 15;
      float4 xv = *(const float4*)&Xb[(size_t)(t0 + r) * kDH + c * 4];
      float wv = wsh[r];
      xv.x *= wv; xv.y *= wv; xv.z *= wv; xv.w *= wv;
      *(float4*)&xs[r][c * 4] = xv;
    }
#pragma unroll
    for (int k = 0; k < 4; ++k) {
      int fid = k * 256 + tid;
      int r = fid >> 5, c = fid & 31;
      *(float4*)&bs[r][c * 4] = *(const float4*)&Bb[(size_t)(t0 + r) * kDS + c * 4];
    }
    __syncthreads();
    for (int tt = 0; tt < 32; ++tt) {
      float4 xv = *(const float4*)&xs[tt][dcol * 4];
#pragma unroll
      for (int m = 0; m < 8; ++m) {
        float b = bs[tt][srow + 16 * m];
        acc[m].x = fmaf(b, xv.x, acc[m].x);
        acc[m].y = fmaf(b, xv.y, acc[m].y);
        acc[m].z = fmaf(b, xv.z, acc[m].z);
        acc[m].w = fmaf(b, xv.w, acc[m].w);
      }
    }
  }
  const float dscale = kAlpha * __expf(alast);
  const float sc = 1.f - kAlpha;
#pragma unroll
  for (int m = 0; m < 8; ++m) {
    int s = srow + 16 * m;
    float4 hv = *(const float4*)&Hb[(size_t)s * kDH + dcol * 4];
    float4 o;
    o.x = dscale * hv.x + sc * acc[m].x;
    o.y = dscale * hv.y + sc * acc[m].y;
    o.z = dscale * hv.z + sc * acc[m].z;
    o.w = dscale * hv.w + sc * acc[m].w;
    *(float4*)&Ob[(size_t)s * kDH + dcol * 4] = o;
  }
}

extern "C" void kernel_launch(void* const* d_in, const int* in_sizes, int n_in,
                              void* d_out, int out_size, void* d_ws, size_t ws_size,
                              hipStream_t stream) {
  const float* X = (const float*)d_in[0];
  const float* A = (const float*)d_in[1];
  const float* B = (const float*)d_in[2];
  const float* C = (const float*)d_in[3];
  const float* H = (const float*)d_in[4];
  float* out = (float*)d_out;
  float* Y = out;
  float* hend = Y + (size_t)kBH * kCS * kDH;
  float* dt = hend + (size_t)kBH * kDS * kDH;

  y_mfma_kernel<<<2048, 256, 0, stream>>>(X, A, B, C, H, Y);
  hend_kernel<<<kBH, 256, 0, stream>>>(X, A, B, H, hend, dt);
}

// Round 4
// 123.250 us; speedup vs baseline: 2.0819x; 2.0819x over previous
//
#include <hip/hip_runtime.h>

typedef __attribute__((ext_vector_type(8))) short s16x8;
typedef __attribute__((ext_vector_type(4))) short s16x4;
typedef __attribute__((ext_vector_type(4))) float f32x4;
typedef __attribute__((ext_vector_type(4))) unsigned u32x4;

namespace {
constexpr int kCS = 256, kDH = 64, kDS = 128, kBH = 512;
constexpr float kAlpha = 0.5f;

// LDS byte offsets (total 30 KB)
constexpr int OFF_AC   = 0;                  // ac: 256 f32
constexpr int OFF_ENEG = 1024;               // eneg: 256 f32
constexpr int OFF_B    = 2048;               // Bhi [32][128] s16 (8KB); aliased by C fp32 bounce (16KB) and HThi half
constexpr int OFF_BLO  = OFF_B + 8192;       // Blo / HTlo
constexpr int OFF_XT   = OFF_B + 16384;      // XThi [64][32] s16 (4KB)
constexpr int OFF_XTLO = OFF_XT + 4096;      // XTlo
constexpr int OFF_S    = OFF_XTLO + 4096;    // S~hi per-wave [16][32] s16, 4 waves (4KB); cumsum partials early
constexpr int LDS_BYTES = OFF_S + 4096;      // 30720
}

union F4 { float4 v; float f[4]; };

// packed f32x2 -> bf16x2 (RNE), 1 VALU inst
__device__ __forceinline__ unsigned cvt_pk_bf16(float a, float b) {
  unsigned r;
  asm("v_cvt_pk_bf16_f32 %0, %1, %2" : "=v"(r) : "v"(a), "v"(b));
  return r;
}

__device__ __forceinline__ unsigned short bf16_1(float x) {
  return (unsigned short)cvt_pk_bf16(x, x);
}

// hi = bf16(a),bf16(b); lo = bf16 of residuals. All static accesses.
__device__ __forceinline__ void split2(float a, float b, unsigned& h, unsigned& l) {
  h = cvt_pk_bf16(a, b);
  l = cvt_pk_bf16(a - __uint_as_float(h << 16), b - __uint_as_float(h & 0xFFFF0000u));
}

__device__ __forceinline__ void split8v(float4 a, float4 b, s16x8& hi, s16x8& lo) {
  unsigned h0, h1, h2, h3, l0, l1, l2, l3;
  split2(a.x, a.y, h0, l0);
  split2(a.z, a.w, h1, l1);
  split2(b.x, b.y, h2, l2);
  split2(b.z, b.w, h3, l3);
  u32x4 H = {h0, h1, h2, h3}, L = {l0, l1, l2, l3};
  hi = __builtin_bit_cast(s16x8, H);
  lo = __builtin_bit_cast(s16x8, L);
}

__device__ __forceinline__ void split8s(float x0, float x1, float x2, float x3,
                                        float x4, float x5, float x6, float x7,
                                        s16x8& hi, s16x8& lo) {
  unsigned h0, h1, h2, h3, l0, l1, l2, l3;
  split2(x0, x1, h0, l0);
  split2(x2, x3, h1, l1);
  split2(x4, x5, h2, l2);
  split2(x6, x7, h3, l3);
  u32x4 H = {h0, h1, h2, h3}, L = {l0, l1, l2, l3};
  hi = __builtin_bit_cast(s16x8, H);
  lo = __builtin_bit_cast(s16x8, L);
}

// LDS ping-pong scan for hend_kernel (unchanged path)
__device__ __forceinline__ void cumsum256(const float* __restrict__ Ab, float* ac, int tid) {
  ac[tid] = Ab[tid];
  __syncthreads();
  for (int off = 1; off < kCS; off <<= 1) {
    float v = ac[tid];
    if (tid >= off) v += ac[tid - off];
    __syncthreads();
    ac[tid] = v;
    __syncthreads();
  }
}

// barrier that waits only this wave's LDS ops -> prefetch vmcnt stays in flight
__device__ __forceinline__ void lds_barrier() {
  asm volatile("s_waitcnt lgkmcnt(0)" ::: "memory");
  __builtin_amdgcn_s_barrier();
  __builtin_amdgcn_sched_barrier(0);
}

// Y[i,d] = (1-a)*sum_{j<=i} exp(ac_i-ac_j)*CB[i,j]*X[j,d] + a*exp(ac_i)*(C·h_prev)[i,d]
// launch_bounds(256,4): 128-VGPR cap. (256,5)'s 102 cap forced the depth-1
// prefetch regs (~24 VGPR on top of ~80 base) to spill to scratch every
// iteration (R2/R3: +500MB HBM traffic). 4 blocks/CU still resident.
__global__ __launch_bounds__(256, 4) void y_mfma_kernel(
    const float* __restrict__ Xg, const float* __restrict__ Ag,
    const float* __restrict__ Bg, const float* __restrict__ Cg,
    const float* __restrict__ Hg, float* __restrict__ Yg) {
  __shared__ __align__(16) char smem[LDS_BYTES];
  float* ac   = (float*)(smem + OFF_AC);
  float* eneg = (float*)(smem + OFF_ENEG);
  short* Bhi  = (short*)(smem + OFF_B);
  short* Blo  = (short*)(smem + OFF_BLO);
  short* XThi = (short*)(smem + OFF_XT);
  short* XTlo = (short*)(smem + OFF_XTLO);
  short* Sall = (short*)(smem + OFF_S);
  float* Cb   = (float*)(smem + OFF_B);   // fp32 bounce, aliases Bhi+Blo (16KB)
  short* HThi = Bhi;                      // h_prev^T half-planes alias B planes
  short* HTlo = Blo;

  const int bidx = blockIdx.x;
  const int it = 3 - (bidx >> 9);   // heavy tiles dispatched first
  const int bh = bidx & 511;
  const int tid = threadIdx.x;
  const int lane = tid & 63;
  const int w = tid >> 6;
  const int fr = lane & 15;   // fragment free-index (A row / B col / D col)
  const int fg = lane >> 4;   // fragment k-group

  const float* Xb = Xg + (size_t)bh * kCS * kDH;
  const float* Ab = Ag + (size_t)bh * kCS;
  const float* Bb = Bg + (size_t)bh * kCS * kDS;
  const float* Cg_b = Cg + (size_t)bh * kCS * kDS;
  const float* Hb = Hg + (size_t)bh * kDS * kDH;
  float* Yb = Yg + (size_t)bh * kCS * kDH;

  // ---- cumsum via wave shuffle scan
  {
    float v = Ab[tid];
#pragma unroll
    for (int off = 1; off < 64; off <<= 1) {
      float t = __shfl_up(v, off);
      if (lane >= off) v += t;
    }
    float* wsum = (float*)(smem + OFF_S);
    if (lane == 63) wsum[w] = v;
    __syncthreads();
    float base = 0.f;
#pragma unroll
    for (int k = 0; k < 4; ++k)
      if (k < w) base += wsum[k];
    const float a = v + base;
    ac[tid] = a;
    eneg[tid] = __expf(-a);
    __syncthreads();
  }

  const int i0 = it * 64;
  float eaci[4];
#pragma unroll
  for (int r = 0; r < 4; ++r) eaci[r] = __expf(ac[i0 + w * 16 + fg * 4 + r]);

  // ---- issue jt=0 prefetch early: latency hides under the C-bounce phase
  const int prow = tid >> 4;
  const int pg = tid & 15;
  float4 pb0, pb1, pb2, pb3;
  float px0, px1, px2, px3, px4, px5, px6, px7;
  {
    pb0 = *(const float4*)&Bb[(size_t)prow * kDS + pg * 8];
    pb1 = *(const float4*)&Bb[(size_t)prow * kDS + pg * 8 + 4];
    pb2 = *(const float4*)&Bb[(size_t)(16 + prow) * kDS + pg * 8];
    pb3 = *(const float4*)&Bb[(size_t)(16 + prow) * kDS + pg * 8 + 4];
    const float* xp = &Xb[(size_t)(w * 8) * kDH + lane];
    px0 = xp[0 * kDH]; px1 = xp[1 * kDH]; px2 = xp[2 * kDH]; px3 = xp[3 * kDH];
    px4 = xp[4 * kDH]; px5 = xp[5 * kDH]; px6 = xp[6 * kDH]; px7 = xp[7 * kDH];
  }

  // ---- C bounce in two 32-row halves: global (coalesced) -> LDS fp32 (16B-block XOR swizzle)
  s16x8 chi[4], clo[4];
#pragma unroll
  for (int m = 0; m < 2; ++m) {
#pragma unroll
    for (int k = 0; k < 4; ++k) {
      int fid = k * 256 + tid;
      int r = fid >> 5, c = fid & 31;
      *(float4*)&Cb[r * 128 + ((c ^ (r & 7)) << 2)] =
          *(const float4*)&Cg_b[(size_t)(i0 + m * 32 + r) * kDS + c * 4];
    }
    __syncthreads();
    if ((w >> 1) == m) {
      const int lrow = (w & 1) * 16 + fr;
      const float* crow = &Cb[lrow * 128];
      const int r7 = lrow & 7;
#pragma unroll
      for (int kc = 0; kc < 4; ++kc) {
        const int c0 = kc * 8 + fg * 2;
        F4 u0, u1;
        u0.v = *(const float4*)&crow[(c0 ^ r7) << 2];
        u1.v = *(const float4*)&crow[((c0 + 1) ^ r7) << 2];
        split8v(u0.v, u1.v, chi[kc], clo[kc]);
      }
    }
    __syncthreads();
  }

  f32x4 yacc[4];
#pragma unroll
  for (int n = 0; n < 4; ++n)
#pragma unroll
    for (int r = 0; r < 4; ++r) yacc[n][r] = 0.f;

  short* Sp = Sall + w * 512;  // per-wave S~ plane [16][32]

  const int jt_n = 2 * it + 2;

  for (int jt = 0; jt < jt_n; ++jt) {
    // ---- split+write current tile from named prefetch regs
    {
      s16x8 h8, l8;
      split8v(pb0, pb1, h8, l8);
      int col = (pg ^ (prow & 7)) * 8;
      *(s16x8*)&Bhi[prow * 128 + col] = h8;
      *(s16x8*)&Blo[prow * 128 + col] = l8;
      const int row1 = 16 + prow;
      split8v(pb2, pb3, h8, l8);
      col = (pg ^ (row1 & 7)) * 8;
      *(s16x8*)&Bhi[row1 * 128 + col] = h8;
      *(s16x8*)&Blo[row1 * 128 + col] = l8;
    }
    {
      s16x8 h8, l8;
      split8s(px0, px1, px2, px3, px4, px5, px6, px7, h8, l8);
      const int d = lane;
      const int off = d * 32 + ((w ^ ((d >> 2) & 3)) << 3);
      *(s16x8*)&XThi[off] = h8;
      *(s16x8*)&XTlo[off] = l8;
    }
    // ---- issue next tile's loads; they stay in flight across both lds_barriers
    if (jt + 1 < jt_n) {
      const int j0n = (jt + 1) * 32;
      pb0 = *(const float4*)&Bb[(size_t)(j0n + prow) * kDS + pg * 8];
      pb1 = *(const float4*)&Bb[(size_t)(j0n + prow) * kDS + pg * 8 + 4];
      pb2 = *(const float4*)&Bb[(size_t)(j0n + 16 + prow) * kDS + pg * 8];
      pb3 = *(const float4*)&Bb[(size_t)(j0n + 16 + prow) * kDS + pg * 8 + 4];
      const float* xp = &Xb[(size_t)(j0n + w * 8) * kDH + lane];
      px0 = xp[0 * kDH]; px1 = xp[1 * kDH]; px2 = xp[2 * kDH]; px3 = xp[3 * kDH];
      px4 = xp[4 * kDH]; px5 = xp[5 * kDH]; px6 = xp[6 * kDH]; px7 = xp[7 * kDH];
    }
    lds_barrier();

    const int j0 = jt * 32;
    // ---- S = C·B^T  (split: Chi·Bhi + Chi·Blo + Clo·Bhi)
    f32x4 s[2];
#pragma unroll
    for (int n = 0; n < 2; ++n) {
#pragma unroll
      for (int r = 0; r < 4; ++r) s[n][r] = 0.f;
      const int jrow = n * 16 + fr;
      const short* bph = &Bhi[jrow * 128];
      const short* bpl = &Blo[jrow * 128];
#pragma unroll
      for (int kc = 0; kc < 4; ++kc) {
        const int phys = ((4 * kc + fg) ^ (jrow & 7)) * 8;
        s16x8 b8 = *(const s16x8*)&bph[phys];
        s16x8 l8 = *(const s16x8*)&bpl[phys];
        s[n] = __builtin_amdgcn_mfma_f32_16x16x32_bf16(chi[kc], b8, s[n], 0, 0, 0);
        s[n] = __builtin_amdgcn_mfma_f32_16x16x32_bf16(chi[kc], l8, s[n], 0, 0, 0);
        s[n] = __builtin_amdgcn_mfma_f32_16x16x32_bf16(clo[kc], b8, s[n], 0, 0, 0);
      }
    }
    // ---- mask + decay, write S~ (bf16 hi) to per-wave plane (block-XOR swizzle)
#pragma unroll
    for (int n = 0; n < 2; ++n) {
      const int jg = j0 + n * 16 + fr;
      const float enj = eneg[jg];
#pragma unroll
      for (int r = 0; r < 4; ++r) {
        const int iwl = fg * 4 + r;
        const int ig = i0 + w * 16 + iwl;
        float sv = s[n][r] * eaci[r] * enj;
        sv = (jg <= ig) ? sv : 0.f;
        Sp[iwl * 32 + (((n * 2 + (fr >> 3)) ^ fg) << 3) + (fr & 7)] = (short)bf16_1(sv);
      }
    }
    // ---- PV: Y += S~ · X   (S~hi·Xhi + S~hi·Xlo)
    {
      s16x8 sa = *(const s16x8*)&Sp[fr * 32 + ((fg ^ (fr >> 2)) << 3)];
#pragma unroll
      for (int n = 0; n < 4; ++n) {
        const int drow = n * 16 + fr;
        const int pxo = (fg ^ ((drow >> 2) & 3)) << 3;
        s16x8 xh = *(const s16x8*)&XThi[drow * 32 + pxo];
        s16x8 xl = *(const s16x8*)&XTlo[drow * 32 + pxo];
        yacc[n] = __builtin_amdgcn_mfma_f32_16x16x32_bf16(sa, xh, yacc[n], 0, 0, 0);
        yacc[n] = __builtin_amdgcn_mfma_f32_16x16x32_bf16(sa, xl, yacc[n], 0, 0, 0);
      }
    }
    lds_barrier();
  }

  // ---- Yh = C · h_prev in two s-halves (HT half-plane aliases B planes, 16KB)
  f32x4 yh[4];
#pragma unroll
  for (int n = 0; n < 4; ++n)
#pragma unroll
    for (int r = 0; r < 4; ++r) yh[n][r] = 0.f;

#pragma unroll
  for (int m = 0; m < 2; ++m) {
    // stage h_prev^T half: h[64s][64d] -> HT[d][s_local] hi/lo
    {
      const int dd = tid & 15, tt = tid >> 4;
      F4 hr[4];
#pragma unroll
      for (int r = 0; r < 4; ++r)
        hr[r].v = *(const float4*)&Hb[(size_t)(m * 64 + tt * 4 + r) * kDH + dd * 4];
#pragma unroll
      for (int c = 0; c < 4; ++c) {
        const int d = dd * 4 + c;
        unsigned h0, h1, l0, l1;
        split2(hr[0].f[c], hr[1].f[c], h0, l0);
        split2(hr[2].f[c], hr[3].f[c], h1, l1);
        const int off = d * 64 + (((tt >> 1) ^ (d & 7)) << 3) + ((tt & 1) << 2);
        ((unsigned*)&HThi[off])[0] = h0;
        ((unsigned*)&HThi[off])[1] = h1;
        ((unsigned*)&HTlo[off])[0] = l0;
        ((unsigned*)&HTlo[off])[1] = l1;
      }
    }
    __syncthreads();
#pragma unroll
    for (int kcl = 0; kcl < 2; ++kcl) {
      const int kc = m * 2 + kcl;
#pragma unroll
      for (int n = 0; n < 4; ++n) {
        const int drow = n * 16 + fr;
        const int phys = ((4 * kcl + fg) ^ (drow & 7)) * 8;
        s16x8 hh = *(const s16x8*)&HThi[drow * 64 + phys];
        s16x8 hl = *(const s16x8*)&HTlo[drow * 64 + phys];
        yh[n] = __builtin_amdgcn_mfma_f32_16x16x32_bf16(chi[kc], hh, yh[n], 0, 0, 0);
        yh[n] = __builtin_amdgcn_mfma_f32_16x16x32_bf16(chi[kc], hl, yh[n], 0, 0, 0);
        yh[n] = __builtin_amdgcn_mfma_f32_16x16x32_bf16(clo[kc], hh, yh[n], 0, 0, 0);
      }
    }
    if (m == 0) __syncthreads();  // before half-1 staging overwrites HT
  }

  // ---- epilogue: Y = (1-a)*Y_intra + a*exp(ac_i)*Yh
#pragma unroll
  for (int n = 0; n < 4; ++n) {
#pragma unroll
    for (int r = 0; r < 4; ++r) {
      const int ig = i0 + w * 16 + fg * 4 + r;
      const int d = n * 16 + fr;
      Yb[(size_t)ig * kDH + d] = (1.f - kAlpha) * yacc[n][r] + (kAlpha * eaci[r]) * yh[n][r];
    }
  }
}

// h_end[s,d] = alpha*decay_total*h_prev[s,d] + (1-alpha)*sum_t B[t,s]*w_t*X[t,d]
__global__ __launch_bounds__(256, 2) void hend_kernel(
    const float* __restrict__ Xg, const float* __restrict__ Ag,
    const float* __restrict__ Bg, const float* __restrict__ Hg,
    float* __restrict__ hend, float* __restrict__ dtot) {
  const int bh = blockIdx.x;
  const int tid = threadIdx.x;
  const float* Xb = Xg + (size_t)bh * kCS * kDH;
  const float* Ab = Ag + (size_t)bh * kCS;
  const float* Bb = Bg + (size_t)bh * kCS * kDS;
  const float* Hb = Hg + (size_t)bh * kDS * kDH;
  float* Ob = hend + (size_t)bh * kDS * kDH;

  __shared__ float ac[kCS];
  __shared__ float wsh[32];
  __shared__ float xs[32][kDH];
  __shared__ float bs[32][kDS];

  cumsum256(Ab, ac, tid);
  const float alast = ac[kCS - 1];
  if (tid == 0) dtot[bh] = __expf(alast);

  const int dcol = tid & 15;
  const int srow = tid >> 4;
  float4 acc[8];
#pragma unroll
  for (int m = 0; m < 8; ++m) acc[m] = make_float4(0.f, 0.f, 0.f, 0.f);

  for (int t0 = 0; t0 < kCS; t0 += 32) {
    __syncthreads();
    if (tid < 32) wsh[tid] = __expf(alast - ac[t0 + tid]);
    __syncthreads();
#pragma unroll
    for (int k = 0; k < 2; ++k) {
      int fid = k * 256 + tid;
      int r = fid >> 4, c = fid & 15;
      float4 xv = *(const float4*)&Xb[(size_t)(t0 + r) * kDH + c * 4];
      float wv = wsh[r];
      xv.x *= wv; xv.y *= wv; xv.z *= wv; xv.w *= wv;
      *(float4*)&xs[r][c * 4] = xv;
    }
#pragma unroll
    for (int k = 0; k < 4; ++k) {
      int fid = k * 256 + tid;
      int r = fid >> 5, c = fid & 31;
      *(float4*)&bs[r][c * 4] = *(const float4*)&Bb[(size_t)(t0 + r) * kDS + c * 4];
    }
    __syncthreads();
    for (int tt = 0; tt < 32; ++tt) {
      float4 xv = *(const float4*)&xs[tt][dcol * 4];
#pragma unroll
      for (int m = 0; m < 8; ++m) {
        float b = bs[tt][srow + 16 * m];
        acc[m].x = fmaf(b, xv.x, acc[m].x);
        acc[m].y = fmaf(b, xv.y, acc[m].y);
        acc[m].z = fmaf(b, xv.z, acc[m].z);
        acc[m].w = fmaf(b, xv.w, acc[m].w);
      }
    }
  }
  const float dscale = kAlpha * __expf(alast);
  const float sc = 1.f - kAlpha;
#pragma unroll
  for (int m = 0; m < 8; ++m) {
    int s = srow + 16 * m;
    float4 hv = *(const float4*)&Hb[(size_t)s * kDH + dcol * 4];
    float4 o;
    o.x = dscale * hv.x + sc * acc[m].x;
    o.y = dscale * hv.y + sc * acc[m].y;
    o.z = dscale * hv.z + sc * acc[m].z;
    o.w = dscale * hv.w + sc * acc[m].w;
    *(float4*)&Ob[(size_t)s * kDH + dcol * 4] = o;
  }
}

extern "C" void kernel_launch(void* const* d_in, const int* in_sizes, int n_in,
                              void* d_out, int out_size, void* d_ws, size_t ws_size,
                              hipStream_t stream) {
  const float* X = (const float*)d_in[0];
  const float* A = (const float*)d_in[1];
  const float* B = (const float*)d_in[2];
  const float* C = (const float*)d_in[3];
  const float* H = (const float*)d_in[4];
  float* out = (float*)d_out;
  float* Y = out;
  float* hend = Y + (size_t)kBH * kCS * kDH;
  float* dt = hend + (size_t)kBH * kDS * kDH;

  y_mfma_kernel<<<2048, 256, 0, stream>>>(X, A, B, C, H, Y);
  hend_kernel<<<kBH, 256, 0, stream>>>(X, A, B, H, hend, dt);
}

// Round 5
// 101.336 us; speedup vs baseline: 2.5321x; 1.2163x over previous
//
#include <hip/hip_runtime.h>

typedef __attribute__((ext_vector_type(8))) short s16x8;
typedef __attribute__((ext_vector_type(4))) short s16x4;
typedef __attribute__((ext_vector_type(4))) float f32x4;
typedef __attribute__((ext_vector_type(4))) unsigned u32x4;

namespace {
constexpr int kCS = 256, kDH = 64, kDS = 128, kBH = 512;
constexpr float kAlpha = 0.5f;

// y-path LDS byte offsets (total 30 KB)
constexpr int OFF_AC   = 0;                  // ac: 256 f32
constexpr int OFF_ENEG = 1024;               // eneg: 256 f32
constexpr int OFF_B    = 2048;               // Bhi [32][128] s16 (8KB); aliased by C fp32 bounce (16KB) and HThi half
constexpr int OFF_BLO  = OFF_B + 8192;       // Blo / HTlo
constexpr int OFF_XT   = OFF_B + 16384;      // XThi [64][32] s16 (4KB)
constexpr int OFF_XTLO = OFF_XT + 4096;      // XTlo
constexpr int OFF_S    = OFF_XTLO + 4096;    // S~hi per-wave [16][32] s16, 4 waves (4KB); cumsum partials early
constexpr int LDS_BYTES = OFF_S + 4096;      // 30720

// hend-path LDS view (13.3KB, fits inside)
constexpr int HOFF_AC = 0;                   // ac: 256 f32
constexpr int HOFF_W  = 1024;                // wsh: 32 f32
constexpr int HOFF_XS = 2048;                // xs [32][64] f32 (8KB)
constexpr int HOFF_BS = 2048 + 8192;         // bs [32][32] f32 (4KB)
}

union F4 { float4 v; float f[4]; };

// packed f32x2 -> bf16x2 (RNE), 1 VALU inst
__device__ __forceinline__ unsigned cvt_pk_bf16(float a, float b) {
  unsigned r;
  asm("v_cvt_pk_bf16_f32 %0, %1, %2" : "=v"(r) : "v"(a), "v"(b));
  return r;
}

__device__ __forceinline__ unsigned short bf16_1(float x) {
  return (unsigned short)cvt_pk_bf16(x, x);
}

// hi = bf16(a),bf16(b); lo = bf16 of residuals. All static accesses.
__device__ __forceinline__ void split2(float a, float b, unsigned& h, unsigned& l) {
  h = cvt_pk_bf16(a, b);
  l = cvt_pk_bf16(a - __uint_as_float(h << 16), b - __uint_as_float(h & 0xFFFF0000u));
}

__device__ __forceinline__ void split8v(float4 a, float4 b, s16x8& hi, s16x8& lo) {
  unsigned h0, h1, h2, h3, l0, l1, l2, l3;
  split2(a.x, a.y, h0, l0);
  split2(a.z, a.w, h1, l1);
  split2(b.x, b.y, h2, l2);
  split2(b.z, b.w, h3, l3);
  u32x4 H = {h0, h1, h2, h3}, L = {l0, l1, l2, l3};
  hi = __builtin_bit_cast(s16x8, H);
  lo = __builtin_bit_cast(s16x8, L);
}

__device__ __forceinline__ void split8s(float x0, float x1, float x2, float x3,
                                        float x4, float x5, float x6, float x7,
                                        s16x8& hi, s16x8& lo) {
  unsigned h0, h1, h2, h3, l0, l1, l2, l3;
  split2(x0, x1, h0, l0);
  split2(x2, x3, h1, l1);
  split2(x4, x5, h2, l2);
  split2(x6, x7, h3, l3);
  u32x4 H = {h0, h1, h2, h3}, L = {l0, l1, l2, l3};
  hi = __builtin_bit_cast(s16x8, H);
  lo = __builtin_bit_cast(s16x8, L);
}

// barrier that waits only this wave's LDS ops -> prefetch vmcnt stays in flight
__device__ __forceinline__ void lds_barrier() {
  asm volatile("s_waitcnt lgkmcnt(0)" ::: "memory");
  __builtin_amdgcn_s_barrier();
  __builtin_amdgcn_sched_barrier(0);
}

// Fused launch, interleaved: even bidx -> Y block (2048), odd bidx -> hend
// chunk block (2048). Interleave co-schedules latency-bound Y blocks with
// VALU-bound hend blocks on each CU so hend's FMAs fill Y's idle issue slots.
__global__ __launch_bounds__(256, 4) void fused_kernel(
    const float* __restrict__ Xg, const float* __restrict__ Ag,
    const float* __restrict__ Bg, const float* __restrict__ Cg,
    const float* __restrict__ Hg, float* __restrict__ Yg,
    float* __restrict__ hend, float* __restrict__ dtot) {
  __shared__ __align__(16) char smem[LDS_BYTES];
  const int bidx = blockIdx.x;
  const int tid = threadIdx.x;
  const int lane = tid & 63;
  const int w = tid >> 6;

  if (bidx & 1) {
    // ======================= h_end path (s-chunk of 32) =======================
    const int hidx = bidx >> 1;
    const int bh = hidx >> 2;
    const int s0 = (hidx & 3) * 32;

    float* ac  = (float*)(smem + HOFF_AC);
    float* wsh = (float*)(smem + HOFF_W);
    float (*xs)[kDH] = (float(*)[kDH])(smem + HOFF_XS);
    float (*bs)[32] = (float(*)[32])(smem + HOFF_BS);

    const float* Xb = Xg + (size_t)bh * kCS * kDH;
    const float* Ab = Ag + (size_t)bh * kCS;
    const float* Bb = Bg + (size_t)bh * kCS * kDS;
    const float* Hb = Hg + (size_t)bh * kDS * kDH;
    float* Ob = hend + (size_t)bh * kDS * kDH;

    // shuffle-scan cumsum
    {
      float v = Ab[tid];
#pragma unroll
      for (int off = 1; off < 64; off <<= 1) {
        float t = __shfl_up(v, off);
        if (lane >= off) v += t;
      }
      if (lane == 63) wsh[w] = v;
      __syncthreads();
      float base = 0.f;
#pragma unroll
      for (int k = 0; k < 4; ++k)
        if (k < w) base += wsh[k];
      ac[tid] = v + base;
      __syncthreads();
    }
    const float alast = ac[kCS - 1];
    if (s0 == 0 && tid == 0) dtot[bh] = __expf(alast);

    const int dcol = tid & 15;
    const int srow = tid >> 4;
    float4 acc0 = make_float4(0.f, 0.f, 0.f, 0.f);
    float4 acc1 = make_float4(0.f, 0.f, 0.f, 0.f);

    for (int t0 = 0; t0 < kCS; t0 += 32) {
      __syncthreads();
      if (tid < 32) wsh[tid] = __expf(alast - ac[t0 + tid]);
      __syncthreads();
#pragma unroll
      for (int k = 0; k < 2; ++k) {
        int fid = k * 256 + tid;
        int r = fid >> 4, c = fid & 15;
        float4 xv = *(const float4*)&Xb[(size_t)(t0 + r) * kDH + c * 4];
        float wv = wsh[r];
        xv.x *= wv; xv.y *= wv; xv.z *= wv; xv.w *= wv;
        *(float4*)&xs[r][c * 4] = xv;
      }
      {
        int r = tid >> 3, c = tid & 7;
        *(float4*)&bs[r][c * 4] = *(const float4*)&Bb[(size_t)(t0 + r) * kDS + s0 + c * 4];
      }
      __syncthreads();
      for (int tt = 0; tt < 32; ++tt) {
        float4 xv = *(const float4*)&xs[tt][dcol * 4];
        float b0 = bs[tt][srow];
        float b1 = bs[tt][srow + 16];
        acc0.x = fmaf(b0, xv.x, acc0.x);
        acc0.y = fmaf(b0, xv.y, acc0.y);
        acc0.z = fmaf(b0, xv.z, acc0.z);
        acc0.w = fmaf(b0, xv.w, acc0.w);
        acc1.x = fmaf(b1, xv.x, acc1.x);
        acc1.y = fmaf(b1, xv.y, acc1.y);
        acc1.z = fmaf(b1, xv.z, acc1.z);
        acc1.w = fmaf(b1, xv.w, acc1.w);
      }
    }
    const float dscale = kAlpha * __expf(alast);
    const float sc = 1.f - kAlpha;
    {
      int s = s0 + srow;
      float4 hv = *(const float4*)&Hb[(size_t)s * kDH + dcol * 4];
      float4 o;
      o.x = dscale * hv.x + sc * acc0.x;
      o.y = dscale * hv.y + sc * acc0.y;
      o.z = dscale * hv.z + sc * acc0.z;
      o.w = dscale * hv.w + sc * acc0.w;
      *(float4*)&Ob[(size_t)s * kDH + dcol * 4] = o;
      s += 16;
      hv = *(const float4*)&Hb[(size_t)s * kDH + dcol * 4];
      o.x = dscale * hv.x + sc * acc1.x;
      o.y = dscale * hv.y + sc * acc1.y;
      o.z = dscale * hv.z + sc * acc1.z;
      o.w = dscale * hv.w + sc * acc1.w;
      *(float4*)&Ob[(size_t)s * kDH + dcol * 4] = o;
    }
    return;
  }

  // ======================= Y path (identical to R4's y_mfma) =======================
  const int yidx = bidx >> 1;
  const int it = 3 - (yidx >> 9);   // heavy tiles dispatched first
  const int bh = yidx & 511;

  float* ac   = (float*)(smem + OFF_AC);
  float* eneg = (float*)(smem + OFF_ENEG);
  short* Bhi  = (short*)(smem + OFF_B);
  short* Blo  = (short*)(smem + OFF_BLO);
  short* XThi = (short*)(smem + OFF_XT);
  short* XTlo = (short*)(smem + OFF_XTLO);
  short* Sall = (short*)(smem + OFF_S);
  float* Cb   = (float*)(smem + OFF_B);   // fp32 bounce, aliases Bhi+Blo (16KB)
  short* HThi = Bhi;                      // h_prev^T half-planes alias B planes
  short* HTlo = Blo;

  const int fr = lane & 15;   // fragment free-index (A row / B col / D col)
  const int fg = lane >> 4;   // fragment k-group

  const float* Xb = Xg + (size_t)bh * kCS * kDH;
  const float* Ab = Ag + (size_t)bh * kCS;
  const float* Bb = Bg + (size_t)bh * kCS * kDS;
  const float* Cg_b = Cg + (size_t)bh * kCS * kDS;
  const float* Hb = Hg + (size_t)bh * kDS * kDH;
  float* Yb = Yg + (size_t)bh * kCS * kDH;

  // ---- cumsum via wave shuffle scan
  {
    float v = Ab[tid];
#pragma unroll
    for (int off = 1; off < 64; off <<= 1) {
      float t = __shfl_up(v, off);
      if (lane >= off) v += t;
    }
    float* wsum = (float*)(smem + OFF_S);
    if (lane == 63) wsum[w] = v;
    __syncthreads();
    float base = 0.f;
#pragma unroll
    for (int k = 0; k < 4; ++k)
      if (k < w) base += wsum[k];
    const float a = v + base;
    ac[tid] = a;
    eneg[tid] = __expf(-a);
    __syncthreads();
  }

  const int i0 = it * 64;
  float eaci[4];
#pragma unroll
  for (int r = 0; r < 4; ++r) eaci[r] = __expf(ac[i0 + w * 16 + fg * 4 + r]);

  // ---- issue jt=0 prefetch early: latency hides under the C-bounce phase
  const int prow = tid >> 4;
  const int pg = tid & 15;
  float4 pb0, pb1, pb2, pb3;
  float px0, px1, px2, px3, px4, px5, px6, px7;
  {
    pb0 = *(const float4*)&Bb[(size_t)prow * kDS + pg * 8];
    pb1 = *(const float4*)&Bb[(size_t)prow * kDS + pg * 8 + 4];
    pb2 = *(const float4*)&Bb[(size_t)(16 + prow) * kDS + pg * 8];
    pb3 = *(const float4*)&Bb[(size_t)(16 + prow) * kDS + pg * 8 + 4];
    const float* xp = &Xb[(size_t)(w * 8) * kDH + lane];
    px0 = xp[0 * kDH]; px1 = xp[1 * kDH]; px2 = xp[2 * kDH]; px3 = xp[3 * kDH];
    px4 = xp[4 * kDH]; px5 = xp[5 * kDH]; px6 = xp[6 * kDH]; px7 = xp[7 * kDH];
  }

  // ---- C bounce in two 32-row halves: global (coalesced) -> LDS fp32 (16B-block XOR swizzle)
  s16x8 chi[4], clo[4];
#pragma unroll
  for (int m = 0; m < 2; ++m) {
#pragma unroll
    for (int k = 0; k < 4; ++k) {
      int fid = k * 256 + tid;
      int r = fid >> 5, c = fid & 31;
      *(float4*)&Cb[r * 128 + ((c ^ (r & 7)) << 2)] =
          *(const float4*)&Cg_b[(size_t)(i0 + m * 32 + r) * kDS + c * 4];
    }
    __syncthreads();
    if ((w >> 1) == m) {
      const int lrow = (w & 1) * 16 + fr;
      const float* crow = &Cb[lrow * 128];
      const int r7 = lrow & 7;
#pragma unroll
      for (int kc = 0; kc < 4; ++kc) {
        const int c0 = kc * 8 + fg * 2;
        F4 u0, u1;
        u0.v = *(const float4*)&crow[(c0 ^ r7) << 2];
        u1.v = *(const float4*)&crow[((c0 + 1) ^ r7) << 2];
        split8v(u0.v, u1.v, chi[kc], clo[kc]);
      }
    }
    __syncthreads();
  }

  f32x4 yacc[4];
#pragma unroll
  for (int n = 0; n < 4; ++n)
#pragma unroll
    for (int r = 0; r < 4; ++r) yacc[n][r] = 0.f;

  short* Sp = Sall + w * 512;  // per-wave S~ plane [16][32]

  const int jt_n = 2 * it + 2;

  for (int jt = 0; jt < jt_n; ++jt) {
    // ---- split+write current tile from named prefetch regs
    {
      s16x8 h8, l8;
      split8v(pb0, pb1, h8, l8);
      int col = (pg ^ (prow & 7)) * 8;
      *(s16x8*)&Bhi[prow * 128 + col] = h8;
      *(s16x8*)&Blo[prow * 128 + col] = l8;
      const int row1 = 16 + prow;
      split8v(pb2, pb3, h8, l8);
      col = (pg ^ (row1 & 7)) * 8;
      *(s16x8*)&Bhi[row1 * 128 + col] = h8;
      *(s16x8*)&Blo[row1 * 128 + col] = l8;
    }
    {
      s16x8 h8, l8;
      split8s(px0, px1, px2, px3, px4, px5, px6, px7, h8, l8);
      const int d = lane;
      const int off = d * 32 + ((w ^ ((d >> 2) & 3)) << 3);
      *(s16x8*)&XThi[off] = h8;
      *(s16x8*)&XTlo[off] = l8;
    }
    // ---- issue next tile's loads; they stay in flight across both lds_barriers
    if (jt + 1 < jt_n) {
      const int j0n = (jt + 1) * 32;
      pb0 = *(const float4*)&Bb[(size_t)(j0n + prow) * kDS + pg * 8];
      pb1 = *(const float4*)&Bb[(size_t)(j0n + prow) * kDS + pg * 8 + 4];
      pb2 = *(const float4*)&Bb[(size_t)(j0n + 16 + prow) * kDS + pg * 8];
      pb3 = *(const float4*)&Bb[(size_t)(j0n + 16 + prow) * kDS + pg * 8 + 4];
      const float* xp = &Xb[(size_t)(j0n + w * 8) * kDH + lane];
      px0 = xp[0 * kDH]; px1 = xp[1 * kDH]; px2 = xp[2 * kDH]; px3 = xp[3 * kDH];
      px4 = xp[4 * kDH]; px5 = xp[5 * kDH]; px6 = xp[6 * kDH]; px7 = xp[7 * kDH];
    }
    lds_barrier();

    const int j0 = jt * 32;
    // ---- S = C·B^T  (split: Chi·Bhi + Chi·Blo + Clo·Bhi)
    f32x4 s[2];
#pragma unroll
    for (int n = 0; n < 2; ++n) {
#pragma unroll
      for (int r = 0; r < 4; ++r) s[n][r] = 0.f;
      const int jrow = n * 16 + fr;
      const short* bph = &Bhi[jrow * 128];
      const short* bpl = &Blo[jrow * 128];
#pragma unroll
      for (int kc = 0; kc < 4; ++kc) {
        const int phys = ((4 * kc + fg) ^ (jrow & 7)) * 8;
        s16x8 b8 = *(const s16x8*)&bph[phys];
        s16x8 l8 = *(const s16x8*)&bpl[phys];
        s[n] = __builtin_amdgcn_mfma_f32_16x16x32_bf16(chi[kc], b8, s[n], 0, 0, 0);
        s[n] = __builtin_amdgcn_mfma_f32_16x16x32_bf16(chi[kc], l8, s[n], 0, 0, 0);
        s[n] = __builtin_amdgcn_mfma_f32_16x16x32_bf16(clo[kc], b8, s[n], 0, 0, 0);
      }
    }
    // ---- mask + decay, write S~ (bf16 hi) to per-wave plane (block-XOR swizzle)
#pragma unroll
    for (int n = 0; n < 2; ++n) {
      const int jg = j0 + n * 16 + fr;
      const float enj = eneg[jg];
#pragma unroll
      for (int r = 0; r < 4; ++r) {
        const int iwl = fg * 4 + r;
        const int ig = i0 + w * 16 + iwl;
        float sv = s[n][r] * eaci[r] * enj;
        sv = (jg <= ig) ? sv : 0.f;
        Sp[iwl * 32 + (((n * 2 + (fr >> 3)) ^ fg) << 3) + (fr & 7)] = (short)bf16_1(sv);
      }
    }
    // ---- PV: Y += S~ · X   (S~hi·Xhi + S~hi·Xlo)
    {
      s16x8 sa = *(const s16x8*)&Sp[fr * 32 + ((fg ^ (fr >> 2)) << 3)];
#pragma unroll
      for (int n = 0; n < 4; ++n) {
        const int drow = n * 16 + fr;
        const int pxo = (fg ^ ((drow >> 2) & 3)) << 3;
        s16x8 xh = *(const s16x8*)&XThi[drow * 32 + pxo];
        s16x8 xl = *(const s16x8*)&XTlo[drow * 32 + pxo];
        yacc[n] = __builtin_amdgcn_mfma_f32_16x16x32_bf16(sa, xh, yacc[n], 0, 0, 0);
        yacc[n] = __builtin_amdgcn_mfma_f32_16x16x32_bf16(sa, xl, yacc[n], 0, 0, 0);
      }
    }
    lds_barrier();
  }

  // ---- Yh = C · h_prev in two s-halves (HT half-plane aliases B planes, 16KB)
  f32x4 yh[4];
#pragma unroll
  for (int n = 0; n < 4; ++n)
#pragma unroll
    for (int r = 0; r < 4; ++r) yh[n][r] = 0.f;

#pragma unroll
  for (int m = 0; m < 2; ++m) {
    // stage h_prev^T half: h[64s][64d] -> HT[d][s_local] hi/lo
    {
      const int dd = tid & 15, tt = tid >> 4;
      F4 hr[4];
#pragma unroll
      for (int r = 0; r < 4; ++r)
        hr[r].v = *(const float4*)&Hb[(size_t)(m * 64 + tt * 4 + r) * kDH + dd * 4];
#pragma unroll
      for (int c = 0; c < 4; ++c) {
        const int d = dd * 4 + c;
        unsigned h0, h1, l0, l1;
        split2(hr[0].f[c], hr[1].f[c], h0, l0);
        split2(hr[2].f[c], hr[3].f[c], h1, l1);
        const int off = d * 64 + (((tt >> 1) ^ (d & 7)) << 3) + ((tt & 1) << 2);
        ((unsigned*)&HThi[off])[0] = h0;
        ((unsigned*)&HThi[off])[1] = h1;
        ((unsigned*)&HTlo[off])[0] = l0;
        ((unsigned*)&HTlo[off])[1] = l1;
      }
    }
    __syncthreads();
#pragma unroll
    for (int kcl = 0; kcl < 2; ++kcl) {
      const int kc = m * 2 + kcl;
#pragma unroll
      for (int n = 0; n < 4; ++n) {
        const int drow = n * 16 + fr;
        const int phys = ((4 * kcl + fg) ^ (drow & 7)) * 8;
        s16x8 hh = *(const s16x8*)&HThi[drow * 64 + phys];
        s16x8 hl = *(const s16x8*)&HTlo[drow * 64 + phys];
        yh[n] = __builtin_amdgcn_mfma_f32_16x16x32_bf16(chi[kc], hh, yh[n], 0, 0, 0);
        yh[n] = __builtin_amdgcn_mfma_f32_16x16x32_bf16(chi[kc], hl, yh[n], 0, 0, 0);
        yh[n] = __builtin_amdgcn_mfma_f32_16x16x32_bf16(clo[kc], hh, yh[n], 0, 0, 0);
      }
    }
    if (m == 0) __syncthreads();  // before half-1 staging overwrites HT
  }

  // ---- epilogue: Y = (1-a)*Y_intra + a*exp(ac_i)*Yh
#pragma unroll
  for (int n = 0; n < 4; ++n) {
#pragma unroll
    for (int r = 0; r < 4; ++r) {
      const int ig = i0 + w * 16 + fg * 4 + r;
      const int d = n * 16 + fr;
      Yb[(size_t)ig * kDH + d] = (1.f - kAlpha) * yacc[n][r] + (kAlpha * eaci[r]) * yh[n][r];
    }
  }
}

extern "C" void kernel_launch(void* const* d_in, const int* in_sizes, int n_in,
                              void* d_out, int out_size, void* d_ws, size_t ws_size,
                              hipStream_t stream) {
  const float* X = (const float*)d_in[0];
  const float* A = (const float*)d_in[1];
  const float* B = (const float*)d_in[2];
  const float* C = (const float*)d_in[3];
  const float* H = (const float*)d_in[4];
  float* out = (float*)d_out;
  float* Y = out;
  float* hend = Y + (size_t)kBH * kCS * kDH;
  float* dt = hend + (size_t)kBH * kDS * kDH;

  fused_kernel<<<4096, 256, 0, stream>>>(X, A, B, C, H, Y, hend, dt);
}

// Round 6
// 89.562 us; speedup vs baseline: 2.8650x; 1.1315x over previous
//
#include <hip/hip_runtime.h>

typedef __attribute__((ext_vector_type(8))) short s16x8;
typedef __attribute__((ext_vector_type(4))) short s16x4;
typedef __attribute__((ext_vector_type(4))) float f32x4;
typedef __attribute__((ext_vector_type(4))) unsigned u32x4;

namespace {
constexpr int kCS = 256, kDH = 64, kDS = 128, kBH = 512;
constexpr float kAlpha = 0.5f;

// y-path LDS byte offsets (total 30 KB)
constexpr int OFF_AC   = 0;                  // ac: 256 f32
constexpr int OFF_ENEG = 1024;               // eneg: 256 f32
constexpr int OFF_B    = 2048;               // Bhi [32][128] s16 (8KB); aliased by C fp32 bounce (16KB) and HThi half
constexpr int OFF_BLO  = OFF_B + 8192;       // Blo / HTlo
constexpr int OFF_XT   = OFF_B + 16384;      // XThi [64][32] s16 (4KB)
constexpr int OFF_XTLO = OFF_XT + 4096;      // XTlo
constexpr int OFF_S    = OFF_XTLO + 4096;    // S~hi per-wave [16][32] s16, 4 waves (4KB); cumsum partials early
constexpr int LDS_BYTES = OFF_S + 4096;      // 30720

// hend-path LDS view (26KB, fits inside)
constexpr int HOFF_AC   = 0;                 // ac: 256 f32
constexpr int HOFF_BT   = 2048;              // BT^hi [128s][32t] s16 (8KB); wsum aliases pre-staging
constexpr int HOFF_BTLO = HOFF_BT + 8192;    // BT^lo
constexpr int HOFF_XT   = HOFF_BT + 16384;   // XT^hi [64d][32t] s16 (4KB), weighted
constexpr int HOFF_XTLO = HOFF_XT + 4096;    // XT^lo
}

union F4 { float4 v; float f[4]; };

// packed f32x2 -> bf16x2 (RNE), 1 VALU inst
__device__ __forceinline__ unsigned cvt_pk_bf16(float a, float b) {
  unsigned r;
  asm("v_cvt_pk_bf16_f32 %0, %1, %2" : "=v"(r) : "v"(a), "v"(b));
  return r;
}

__device__ __forceinline__ unsigned short bf16_1(float x) {
  return (unsigned short)cvt_pk_bf16(x, x);
}

// hi = bf16(a),bf16(b); lo = bf16 of residuals. All static accesses.
__device__ __forceinline__ void split2(float a, float b, unsigned& h, unsigned& l) {
  h = cvt_pk_bf16(a, b);
  l = cvt_pk_bf16(a - __uint_as_float(h << 16), b - __uint_as_float(h & 0xFFFF0000u));
}

__device__ __forceinline__ void split8v(float4 a, float4 b, s16x8& hi, s16x8& lo) {
  unsigned h0, h1, h2, h3, l0, l1, l2, l3;
  split2(a.x, a.y, h0, l0);
  split2(a.z, a.w, h1, l1);
  split2(b.x, b.y, h2, l2);
  split2(b.z, b.w, h3, l3);
  u32x4 H = {h0, h1, h2, h3}, L = {l0, l1, l2, l3};
  hi = __builtin_bit_cast(s16x8, H);
  lo = __builtin_bit_cast(s16x8, L);
}

__device__ __forceinline__ void split8s(float x0, float x1, float x2, float x3,
                                        float x4, float x5, float x6, float x7,
                                        s16x8& hi, s16x8& lo) {
  unsigned h0, h1, h2, h3, l0, l1, l2, l3;
  split2(x0, x1, h0, l0);
  split2(x2, x3, h1, l1);
  split2(x4, x5, h2, l2);
  split2(x6, x7, h3, l3);
  u32x4 H = {h0, h1, h2, h3}, L = {l0, l1, l2, l3};
  hi = __builtin_bit_cast(s16x8, H);
  lo = __builtin_bit_cast(s16x8, L);
}

// barrier that waits only this wave's LDS ops -> prefetch vmcnt stays in flight
__device__ __forceinline__ void lds_barrier() {
  asm volatile("s_waitcnt lgkmcnt(0)" ::: "memory");
  __builtin_amdgcn_s_barrier();
  __builtin_amdgcn_sched_barrier(0);
}

// Fused, interleaved 3Y:1H. bidx<2048 with (bidx&3)==3 -> hend for bh=bidx>>2;
// else Y. hend is now MFMA-based (B^T·diag(w)·X GEMM), freeing VALU issue
// slots that the latency-bound Y blocks leave idle anyway.
__global__ __launch_bounds__(256, 4) void fused_kernel(
    const float* __restrict__ Xg, const float* __restrict__ Ag,
    const float* __restrict__ Bg, const float* __restrict__ Cg,
    const float* __restrict__ Hg, float* __restrict__ Yg,
    float* __restrict__ hend, float* __restrict__ dtot) {
  __shared__ __align__(16) char smem[LDS_BYTES];
  const int bidx = blockIdx.x;
  const int tid = threadIdx.x;
  const int lane = tid & 63;
  const int w = tid >> 6;
  const int fr = lane & 15;   // fragment free-index
  const int fg = lane >> 4;   // fragment k-group

  if (bidx < 2048 && (bidx & 3) == 3) {
    // ======================= h_end path (MFMA GEMM) =======================
    // hend[s,d] = a*e^alast*h_prev[s,d] + (1-a)*sum_t B[t,s]*w_t*X[t,d]
    const int bh = bidx >> 2;

    float* ac    = (float*)(smem + HOFF_AC);
    short* BThi  = (short*)(smem + HOFF_BT);
    short* BTlo  = (short*)(smem + HOFF_BTLO);
    short* XThi  = (short*)(smem + HOFF_XT);
    short* XTlo  = (short*)(smem + HOFF_XTLO);

    const float* Xb = Xg + (size_t)bh * kCS * kDH;
    const float* Ab = Ag + (size_t)bh * kCS;
    const float* Bb = Bg + (size_t)bh * kCS * kDS;
    const float* Hb = Hg + (size_t)bh * kDS * kDH;
    float* Ob = hend + (size_t)bh * kDS * kDH;

    // shuffle-scan cumsum
    {
      float v = Ab[tid];
#pragma unroll
      for (int off = 1; off < 64; off <<= 1) {
        float t = __shfl_up(v, off);
        if (lane >= off) v += t;
      }
      float* wsum = (float*)(smem + HOFF_BT);
      if (lane == 63) wsum[w] = v;
      __syncthreads();
      float base = 0.f;
#pragma unroll
      for (int k = 0; k < 4; ++k)
        if (k < w) base += wsum[k];
      ac[tid] = v + base;
      __syncthreads();
    }
    const float alast = ac[kCS - 1];
    if (tid == 0) dtot[bh] = __expf(alast);

    f32x4 acc[2][4];
#pragma unroll
    for (int n = 0; n < 2; ++n)
#pragma unroll
      for (int dg = 0; dg < 4; ++dg)
#pragma unroll
        for (int r = 0; r < 4; ++r) acc[n][dg][r] = 0.f;

    const int sblk = tid & 31;   // s 4-block for BT staging
    const int tq = tid >> 5;     // t quad (0..7)

    for (int t0 = 0; t0 < kCS; t0 += 32) {
      // ---- stage B^T [128s][32t] hi/lo via 4x4 micro-transpose
      {
        F4 hr[4];
#pragma unroll
        for (int r = 0; r < 4; ++r)
          hr[r].v = *(const float4*)&Bb[(size_t)(t0 + tq * 4 + r) * kDS + sblk * 4];
#pragma unroll
        for (int c = 0; c < 4; ++c) {
          const int st = sblk * 4 + c;
          unsigned h0, h1, l0, l1;
          split2(hr[0].f[c], hr[1].f[c], h0, l0);
          split2(hr[2].f[c], hr[3].f[c], h1, l1);
          const int off = st * 32 + (((tq >> 1) ^ ((st >> 2) & 3)) << 3) + ((tq & 1) << 2);
          ((unsigned*)&BThi[off])[0] = h0;
          ((unsigned*)&BThi[off])[1] = h1;
          ((unsigned*)&BTlo[off])[0] = l0;
          ((unsigned*)&BTlo[off])[1] = l1;
        }
      }
      // ---- stage weighted X^T [64d][32t] hi/lo; wave w owns t-block w
      {
        const int d = lane;
        const float* xp = &Xb[(size_t)(t0 + w * 8) * kDH + d];
        const float* ap = &ac[t0 + w * 8];
        float w0 = __expf(alast - ap[0]), w1 = __expf(alast - ap[1]);
        float w2 = __expf(alast - ap[2]), w3 = __expf(alast - ap[3]);
        float w4 = __expf(alast - ap[4]), w5 = __expf(alast - ap[5]);
        float w6 = __expf(alast - ap[6]), w7 = __expf(alast - ap[7]);
        s16x8 h8, l8;
        split8s(xp[0 * kDH] * w0, xp[1 * kDH] * w1, xp[2 * kDH] * w2, xp[3 * kDH] * w3,
                xp[4 * kDH] * w4, xp[5 * kDH] * w5, xp[6 * kDH] * w6, xp[7 * kDH] * w7,
                h8, l8);
        const int off = d * 32 + ((w ^ ((d >> 2) & 3)) << 3);
        *(s16x8*)&XThi[off] = h8;
        *(s16x8*)&XTlo[off] = l8;
      }
      __syncthreads();

      // ---- MFMA: acc[n][dg] += BT(s rows) x XT(d rows), split hi/lo
#pragma unroll
      for (int n = 0; n < 2; ++n) {
        const int st = w * 32 + n * 16 + fr;
        const int aoff = st * 32 + ((fg ^ ((st >> 2) & 3)) << 3);
        s16x8 ah = *(const s16x8*)&BThi[aoff];
        s16x8 al = *(const s16x8*)&BTlo[aoff];
#pragma unroll
        for (int dg = 0; dg < 4; ++dg) {
          const int drow = dg * 16 + fr;
          const int xoff = drow * 32 + ((fg ^ ((drow >> 2) & 3)) << 3);
          s16x8 xh = *(const s16x8*)&XThi[xoff];
          s16x8 xl = *(const s16x8*)&XTlo[xoff];
          acc[n][dg] = __builtin_amdgcn_mfma_f32_16x16x32_bf16(ah, xh, acc[n][dg], 0, 0, 0);
          acc[n][dg] = __builtin_amdgcn_mfma_f32_16x16x32_bf16(ah, xl, acc[n][dg], 0, 0, 0);
          acc[n][dg] = __builtin_amdgcn_mfma_f32_16x16x32_bf16(al, xh, acc[n][dg], 0, 0, 0);
        }
      }
      __syncthreads();
    }

    // ---- epilogue: D row = s-sub (fg*4+r), col = d (fr)
    const float dscale = kAlpha * __expf(alast);
    const float sc = 1.f - kAlpha;
#pragma unroll
    for (int n = 0; n < 2; ++n) {
#pragma unroll
      for (int dg = 0; dg < 4; ++dg) {
#pragma unroll
        for (int r = 0; r < 4; ++r) {
          const int s = w * 32 + n * 16 + fg * 4 + r;
          const int d = dg * 16 + fr;
          Ob[(size_t)s * kDH + d] = dscale * Hb[(size_t)s * kDH + d] + sc * acc[n][dg][r];
        }
      }
    }
    return;
  }

  // ======================= Y path =======================
  int yidx;
  if (bidx < 2048) yidx = 3 * (bidx >> 2) + (bidx & 3);
  else yidx = 1536 + (bidx - 2048);
  const int it = 3 - (yidx >> 9);   // heavy tiles dispatched first
  const int bh = yidx & 511;

  float* ac   = (float*)(smem + OFF_AC);
  float* eneg = (float*)(smem + OFF_ENEG);
  short* Bhi  = (short*)(smem + OFF_B);
  short* Blo  = (short*)(smem + OFF_BLO);
  short* XThi = (short*)(smem + OFF_XT);
  short* XTlo = (short*)(smem + OFF_XTLO);
  short* Sall = (short*)(smem + OFF_S);
  float* Cb   = (float*)(smem + OFF_B);   // fp32 bounce, aliases Bhi+Blo (16KB)
  short* HThi = Bhi;                      // h_prev^T half-planes alias B planes
  short* HTlo = Blo;

  const float* Xb = Xg + (size_t)bh * kCS * kDH;
  const float* Ab = Ag + (size_t)bh * kCS;
  const float* Bb = Bg + (size_t)bh * kCS * kDS;
  const float* Cg_b = Cg + (size_t)bh * kCS * kDS;
  const float* Hb = Hg + (size_t)bh * kDS * kDH;
  float* Yb = Yg + (size_t)bh * kCS * kDH;

  // ---- cumsum via wave shuffle scan
  {
    float v = Ab[tid];
#pragma unroll
    for (int off = 1; off < 64; off <<= 1) {
      float t = __shfl_up(v, off);
      if (lane >= off) v += t;
    }
    float* wsum = (float*)(smem + OFF_S);
    if (lane == 63) wsum[w] = v;
    __syncthreads();
    float base = 0.f;
#pragma unroll
    for (int k = 0; k < 4; ++k)
      if (k < w) base += wsum[k];
    const float a = v + base;
    ac[tid] = a;
    eneg[tid] = __expf(-a);
    __syncthreads();
  }

  const int i0 = it * 64;
  float eaci[4];
#pragma unroll
  for (int r = 0; r < 4; ++r) eaci[r] = __expf(ac[i0 + w * 16 + fg * 4 + r]);

  // ---- issue jt=0 prefetch early: latency hides under the C-bounce phase
  const int prow = tid >> 4;
  const int pg = tid & 15;
  float4 pb0, pb1, pb2, pb3;
  float px0, px1, px2, px3, px4, px5, px6, px7;
  {
    pb0 = *(const float4*)&Bb[(size_t)prow * kDS + pg * 8];
    pb1 = *(const float4*)&Bb[(size_t)prow * kDS + pg * 8 + 4];
    pb2 = *(const float4*)&Bb[(size_t)(16 + prow) * kDS + pg * 8];
    pb3 = *(const float4*)&Bb[(size_t)(16 + prow) * kDS + pg * 8 + 4];
    const float* xp = &Xb[(size_t)(w * 8) * kDH + lane];
    px0 = xp[0 * kDH]; px1 = xp[1 * kDH]; px2 = xp[2 * kDH]; px3 = xp[3 * kDH];
    px4 = xp[4 * kDH]; px5 = xp[5 * kDH]; px6 = xp[6 * kDH]; px7 = xp[7 * kDH];
  }

  // ---- C bounce in two 32-row halves: global (coalesced) -> LDS fp32 (16B-block XOR swizzle)
  s16x8 chi[4], clo[4];
#pragma unroll
  for (int m = 0; m < 2; ++m) {
#pragma unroll
    for (int k = 0; k < 4; ++k) {
      int fid = k * 256 + tid;
      int r = fid >> 5, c = fid & 31;
      *(float4*)&Cb[r * 128 + ((c ^ (r & 7)) << 2)] =
          *(const float4*)&Cg_b[(size_t)(i0 + m * 32 + r) * kDS + c * 4];
    }
    __syncthreads();
    if ((w >> 1) == m) {
      const int lrow = (w & 1) * 16 + fr;
      const float* crow = &Cb[lrow * 128];
      const int r7 = lrow & 7;
#pragma unroll
      for (int kc = 0; kc < 4; ++kc) {
        const int c0 = kc * 8 + fg * 2;
        F4 u0, u1;
        u0.v = *(const float4*)&crow[(c0 ^ r7) << 2];
        u1.v = *(const float4*)&crow[((c0 + 1) ^ r7) << 2];
        split8v(u0.v, u1.v, chi[kc], clo[kc]);
      }
    }
    __syncthreads();
  }

  f32x4 yacc[4];
#pragma unroll
  for (int n = 0; n < 4; ++n)
#pragma unroll
    for (int r = 0; r < 4; ++r) yacc[n][r] = 0.f;

  short* Sp = Sall + w * 512;  // per-wave S~ plane [16][32]

  const int jt_n = 2 * it + 2;

  for (int jt = 0; jt < jt_n; ++jt) {
    // ---- split+write current tile from named prefetch regs
    {
      s16x8 h8, l8;
      split8v(pb0, pb1, h8, l8);
      int col = (pg ^ (prow & 7)) * 8;
      *(s16x8*)&Bhi[prow * 128 + col] = h8;
      *(s16x8*)&Blo[prow * 128 + col] = l8;
      const int row1 = 16 + prow;
      split8v(pb2, pb3, h8, l8);
      col = (pg ^ (row1 & 7)) * 8;
      *(s16x8*)&Bhi[row1 * 128 + col] = h8;
      *(s16x8*)&Blo[row1 * 128 + col] = l8;
    }
    {
      s16x8 h8, l8;
      split8s(px0, px1, px2, px3, px4, px5, px6, px7, h8, l8);
      const int d = lane;
      const int off = d * 32 + ((w ^ ((d >> 2) & 3)) << 3);
      *(s16x8*)&XThi[off] = h8;
      *(s16x8*)&XTlo[off] = l8;
    }
    // ---- issue next tile's loads; they stay in flight across both lds_barriers
    if (jt + 1 < jt_n) {
      const int j0n = (jt + 1) * 32;
      pb0 = *(const float4*)&Bb[(size_t)(j0n + prow) * kDS + pg * 8];
      pb1 = *(const float4*)&Bb[(size_t)(j0n + prow) * kDS + pg * 8 + 4];
      pb2 = *(const float4*)&Bb[(size_t)(j0n + 16 + prow) * kDS + pg * 8];
      pb3 = *(const float4*)&Bb[(size_t)(j0n + 16 + prow) * kDS + pg * 8 + 4];
      const float* xp = &Xb[(size_t)(j0n + w * 8) * kDH + lane];
      px0 = xp[0 * kDH]; px1 = xp[1 * kDH]; px2 = xp[2 * kDH]; px3 = xp[3 * kDH];
      px4 = xp[4 * kDH]; px5 = xp[5 * kDH]; px6 = xp[6 * kDH]; px7 = xp[7 * kDH];
    }
    lds_barrier();

    const int j0 = jt * 32;
    // ---- S = C·B^T, split hi/lo products, and split accumulator chains
    // (sA over kc 0-1, sB over kc 2-3: 4 independent 6-deep MFMA chains)
    f32x4 sA[2], sB[2];
#pragma unroll
    for (int n = 0; n < 2; ++n) {
#pragma unroll
      for (int r = 0; r < 4; ++r) { sA[n][r] = 0.f; sB[n][r] = 0.f; }
      const int jrow = n * 16 + fr;
      const short* bph = &Bhi[jrow * 128];
      const short* bpl = &Blo[jrow * 128];
#pragma unroll
      for (int kc = 0; kc < 2; ++kc) {
        const int phys = ((4 * kc + fg) ^ (jrow & 7)) * 8;
        s16x8 b8 = *(const s16x8*)&bph[phys];
        s16x8 l8 = *(const s16x8*)&bpl[phys];
        sA[n] = __builtin_amdgcn_mfma_f32_16x16x32_bf16(chi[kc], b8, sA[n], 0, 0, 0);
        sA[n] = __builtin_amdgcn_mfma_f32_16x16x32_bf16(chi[kc], l8, sA[n], 0, 0, 0);
        sA[n] = __builtin_amdgcn_mfma_f32_16x16x32_bf16(clo[kc], b8, sA[n], 0, 0, 0);
      }
#pragma unroll
      for (int kc = 2; kc < 4; ++kc) {
        const int phys = ((4 * kc + fg) ^ (jrow & 7)) * 8;
        s16x8 b8 = *(const s16x8*)&bph[phys];
        s16x8 l8 = *(const s16x8*)&bpl[phys];
        sB[n] = __builtin_amdgcn_mfma_f32_16x16x32_bf16(chi[kc], b8, sB[n], 0, 0, 0);
        sB[n] = __builtin_amdgcn_mfma_f32_16x16x32_bf16(chi[kc], l8, sB[n], 0, 0, 0);
        sB[n] = __builtin_amdgcn_mfma_f32_16x16x32_bf16(clo[kc], b8, sB[n], 0, 0, 0);
      }
    }
    // ---- mask + decay, write S~ (bf16 hi) to per-wave plane (block-XOR swizzle)
#pragma unroll
    for (int n = 0; n < 2; ++n) {
      const int jg = j0 + n * 16 + fr;
      const float enj = eneg[jg];
#pragma unroll
      for (int r = 0; r < 4; ++r) {
        const int iwl = fg * 4 + r;
        const int ig = i0 + w * 16 + iwl;
        float sv = (sA[n][r] + sB[n][r]) * eaci[r] * enj;
        sv = (jg <= ig) ? sv : 0.f;
        Sp[iwl * 32 + (((n * 2 + (fr >> 3)) ^ fg) << 3) + (fr & 7)] = (short)bf16_1(sv);
      }
    }
    // ---- PV: Y += S~ · X   (S~hi·Xhi + S~hi·Xlo)
    {
      s16x8 sa = *(const s16x8*)&Sp[fr * 32 + ((fg ^ (fr >> 2)) << 3)];
#pragma unroll
      for (int n = 0; n < 4; ++n) {
        const int drow = n * 16 + fr;
        const int pxo = (fg ^ ((drow >> 2) & 3)) << 3;
        s16x8 xh = *(const s16x8*)&XThi[drow * 32 + pxo];
        s16x8 xl = *(const s16x8*)&XTlo[drow * 32 + pxo];
        yacc[n] = __builtin_amdgcn_mfma_f32_16x16x32_bf16(sa, xh, yacc[n], 0, 0, 0);
        yacc[n] = __builtin_amdgcn_mfma_f32_16x16x32_bf16(sa, xl, yacc[n], 0, 0, 0);
      }
    }
    lds_barrier();
  }

  // ---- Yh = C · h_prev in two s-halves (HT half-plane aliases B planes, 16KB)
  f32x4 yh[4];
#pragma unroll
  for (int n = 0; n < 4; ++n)
#pragma unroll
    for (int r = 0; r < 4; ++r) yh[n][r] = 0.f;

#pragma unroll
  for (int m = 0; m < 2; ++m) {
    // stage h_prev^T half: h[64s][64d] -> HT[d][s_local] hi/lo
    {
      const int dd = tid & 15, tt = tid >> 4;
      F4 hr[4];
#pragma unroll
      for (int r = 0; r < 4; ++r)
        hr[r].v = *(const float4*)&Hb[(size_t)(m * 64 + tt * 4 + r) * kDH + dd * 4];
#pragma unroll
      for (int c = 0; c < 4; ++c) {
        const int d = dd * 4 + c;
        unsigned h0, h1, l0, l1;
        split2(hr[0].f[c], hr[1].f[c], h0, l0);
        split2(hr[2].f[c], hr[3].f[c], h1, l1);
        const int off = d * 64 + (((tt >> 1) ^ (d & 7)) << 3) + ((tt & 1) << 2);
        ((unsigned*)&HThi[off])[0] = h0;
        ((unsigned*)&HThi[off])[1] = h1;
        ((unsigned*)&HTlo[off])[0] = l0;
        ((unsigned*)&HTlo[off])[1] = l1;
      }
    }
    __syncthreads();
#pragma unroll
    for (int kcl = 0; kcl < 2; ++kcl) {
      const int kc = m * 2 + kcl;
#pragma unroll
      for (int n = 0; n < 4; ++n) {
        const int drow = n * 16 + fr;
        const int phys = ((4 * kcl + fg) ^ (drow & 7)) * 8;
        s16x8 hh = *(const s16x8*)&HThi[drow * 64 + phys];
        s16x8 hl = *(const s16x8*)&HTlo[drow * 64 + phys];
        yh[n] = __builtin_amdgcn_mfma_f32_16x16x32_bf16(chi[kc], hh, yh[n], 0, 0, 0);
        yh[n] = __builtin_amdgcn_mfma_f32_16x16x32_bf16(chi[kc], hl, yh[n], 0, 0, 0);
        yh[n] = __builtin_amdgcn_mfma_f32_16x16x32_bf16(clo[kc], hh, yh[n], 0, 0, 0);
      }
    }
    if (m == 0) __syncthreads();  // before half-1 staging overwrites HT
  }

  // ---- epilogue: Y = (1-a)*Y_intra + a*exp(ac_i)*Yh
#pragma unroll
  for (int n = 0; n < 4; ++n) {
#pragma unroll
    for (int r = 0; r < 4; ++r) {
      const int ig = i0 + w * 16 + fg * 4 + r;
      const int d = n * 16 + fr;
      Yb[(size_t)ig * kDH + d] = (1.f - kAlpha) * yacc[n][r] + (kAlpha * eaci[r]) * yh[n][r];
    }
  }
}

extern "C" void kernel_launch(void* const* d_in, const int* in_sizes, int n_in,
                              void* d_out, int out_size, void* d_ws, size_t ws_size,
                              hipStream_t stream) {
  const float* X = (const float*)d_in[0];
  const float* A = (const float*)d_in[1];
  const float* B = (const float*)d_in[2];
  const float* C = (const float*)d_in[3];
  const float* H = (const float*)d_in[4];
  float* out = (float*)d_out;
  float* Y = out;
  float* hend = Y + (size_t)kBH * kCS * kDH;
  float* dt = hend + (size_t)kBH * kDS * kDH;

  fused_kernel<<<2560, 256, 0, stream>>>(X, A, B, C, H, Y, hend, dt);
}

// Round 7
// 79.572 us; speedup vs baseline: 3.2247x; 1.1255x over previous
//
#include <hip/hip_runtime.h>

typedef __attribute__((ext_vector_type(8))) short s16x8;
typedef __attribute__((ext_vector_type(4))) float f32x4;
typedef __attribute__((ext_vector_type(4))) unsigned u32x4;

namespace {
constexpr int kCS = 256, kDH = 64, kDS = 128, kBH = 512;
constexpr float kAlpha = 0.5f;

// Y-path LDS (34816 B)
constexpr int OFF_AC   = 0;                  // ac: 256 f32
constexpr int OFF_ENEG = 1024;               // eneg: 256 f32
constexpr int OFF_B    = 2048;               // Bhi [32][128] s16 (8KB); CbA fp32 bounce (16KB) & HThi [64][128] (16KB) alias B+BLO
constexpr int OFF_BLO  = OFF_B + 8192;       // Blo
constexpr int OFF_XT   = OFF_B + 16384;      // XThi [64][32] s16 (4KB); CbB bounce (16KB) & HTlo (16KB) alias XT..S end
constexpr int OFF_XTLO = OFF_XT + 4096;      // XTlo
constexpr int OFF_S    = OFF_XTLO + 4096;    // S~hi per-wave [16][32] s16, 8 waves (8KB); cumsum partials early
constexpr int LDS_BYTES = OFF_S + 8192;      // 34816

// hend-path aliases
constexpr int HOFF_BT   = 2048;              // BThi [128][32] s16 (8KB)
constexpr int HOFF_BTLO = HOFF_BT + 8192;
constexpr int HOFF_XT   = HOFF_BT + 16384;   // weighted XT [64][32]
constexpr int HOFF_XTLO = HOFF_XT + 4096;
}

union F4 { float4 v; float f[4]; };

// packed f32x2 -> bf16x2 (RNE), 1 VALU inst
__device__ __forceinline__ unsigned cvt_pk_bf16(float a, float b) {
  unsigned r;
  asm("v_cvt_pk_bf16_f32 %0, %1, %2" : "=v"(r) : "v"(a), "v"(b));
  return r;
}

__device__ __forceinline__ unsigned short bf16_1(float x) {
  return (unsigned short)cvt_pk_bf16(x, x);
}

__device__ __forceinline__ void split2(float a, float b, unsigned& h, unsigned& l) {
  h = cvt_pk_bf16(a, b);
  l = cvt_pk_bf16(a - __uint_as_float(h << 16), b - __uint_as_float(h & 0xFFFF0000u));
}

__device__ __forceinline__ void split8v(float4 a, float4 b, s16x8& hi, s16x8& lo) {
  unsigned h0, h1, h2, h3, l0, l1, l2, l3;
  split2(a.x, a.y, h0, l0);
  split2(a.z, a.w, h1, l1);
  split2(b.x, b.y, h2, l2);
  split2(b.z, b.w, h3, l3);
  u32x4 H = {h0, h1, h2, h3}, L = {l0, l1, l2, l3};
  hi = __builtin_bit_cast(s16x8, H);
  lo = __builtin_bit_cast(s16x8, L);
}

__device__ __forceinline__ void split8s(float x0, float x1, float x2, float x3,
                                        float x4, float x5, float x6, float x7,
                                        s16x8& hi, s16x8& lo) {
  unsigned h0, h1, h2, h3, l0, l1, l2, l3;
  split2(x0, x1, h0, l0);
  split2(x2, x3, h1, l1);
  split2(x4, x5, h2, l2);
  split2(x6, x7, h3, l3);
  u32x4 H = {h0, h1, h2, h3}, L = {l0, l1, l2, l3};
  hi = __builtin_bit_cast(s16x8, H);
  lo = __builtin_bit_cast(s16x8, L);
}

// barrier that waits only this wave's LDS ops -> prefetch vmcnt stays in flight
__device__ __forceinline__ void lds_barrier() {
  asm volatile("s_waitcnt lgkmcnt(0)" ::: "memory");
  __builtin_amdgcn_s_barrier();
  __builtin_amdgcn_sched_barrier(0);
}

// 512-thread blocks. Per bh: role0 = Y pair (i-tiles 0,3), role1 = Y pair
// (1,2), role2 = hend. Waves 0-3 compute tile A, waves 4-7 tile B; one shared
// B/X staging stream (20 -> 14 j-tile stagings per bh), one shared H staging.
__global__ __launch_bounds__(512, 4) void fused_kernel(
    const float* __restrict__ Xg, const float* __restrict__ Ag,
    const float* __restrict__ Bg, const float* __restrict__ Cg,
    const float* __restrict__ Hg, float* __restrict__ Yg,
    float* __restrict__ hend, float* __restrict__ dtot) {
  __shared__ __align__(16) char smem[LDS_BYTES];
  const int bidx = blockIdx.x;
  const int tid = threadIdx.x;
  const int lane = tid & 63;
  const int w = tid >> 6;          // 0..7
  const int fr = lane & 15;
  const int fg = lane >> 4;

  // XCD-grouping swizzle: 1536 = 8 XCDs x 192; the 3 blocks of one bh get
  // consecutive swz -> same XCD chunk -> shared L2 for B/C/X/H.
  const int swz = (bidx & 7) * 192 + (bidx >> 3);
  const int role = swz % 3;
  const int bh = swz / 3;

  const float* Xb = Xg + (size_t)bh * kCS * kDH;
  const float* Ab = Ag + (size_t)bh * kCS;
  const float* Bb = Bg + (size_t)bh * kCS * kDS;
  const float* Hb = Hg + (size_t)bh * kDS * kDH;

  if (role == 2) {
    // ======================= h_end path (8-wave MFMA GEMM) =======================
    float* ac   = (float*)(smem + OFF_AC);
    short* BThi = (short*)(smem + HOFF_BT);
    short* BTlo = (short*)(smem + HOFF_BTLO);
    short* XThi = (short*)(smem + HOFF_XT);
    short* XTlo = (short*)(smem + HOFF_XTLO);
    float* Ob = hend + (size_t)bh * kDS * kDH;

    float v = 0.f;
    if (tid < 256) {
      v = Ab[tid];
#pragma unroll
      for (int off = 1; off < 64; off <<= 1) {
        float t = __shfl_up(v, off);
        if (lane >= off) v += t;
      }
      float* wsum = (float*)(smem + HOFF_BT);
      if (lane == 63) wsum[w] = v;
    }
    __syncthreads();
    if (tid < 256) {
      const float* wsum = (const float*)(smem + HOFF_BT);
      float base = 0.f;
#pragma unroll
      for (int k = 0; k < 4; ++k)
        if (k < w) base += wsum[k];
      ac[tid] = v + base;
    }
    __syncthreads();
    const float alast = ac[kCS - 1];
    if (tid == 0) dtot[bh] = __expf(alast);

    f32x4 acc[4];
#pragma unroll
    for (int dg = 0; dg < 4; ++dg)
#pragma unroll
      for (int r = 0; r < 4; ++r) acc[dg][r] = 0.f;

    const int sblk = tid & 31;
    const int tq = (tid >> 5) & 7;
    const int st = w * 16 + fr;

    for (int t0 = 0; t0 < kCS; t0 += 32) {
      if (tid < 256) {
        // stage B^T [128s][32t] hi/lo via 4x4 micro-transpose
        F4 hr[4];
#pragma unroll
        for (int r = 0; r < 4; ++r)
          hr[r].v = *(const float4*)&Bb[(size_t)(t0 + tq * 4 + r) * kDS + sblk * 4];
#pragma unroll
        for (int c = 0; c < 4; ++c) {
          const int s2 = sblk * 4 + c;
          unsigned h0, h1, l0, l1;
          split2(hr[0].f[c], hr[1].f[c], h0, l0);
          split2(hr[2].f[c], hr[3].f[c], h1, l1);
          const int off = s2 * 32 + (((tq >> 1) ^ ((s2 >> 2) & 3)) << 3) + ((tq & 1) << 2);
          ((unsigned*)&BThi[off])[0] = h0;
          ((unsigned*)&BThi[off])[1] = h1;
          ((unsigned*)&BTlo[off])[0] = l0;
          ((unsigned*)&BTlo[off])[1] = l1;
        }
      } else {
        // stage weighted X^T [64d][32t] hi/lo
        const int t2 = tid - 256;
        const int d = t2 & 63;
        const int wx = t2 >> 6;
        const float* xp = &Xb[(size_t)(t0 + wx * 8) * kDH + d];
        const float* ap = &ac[t0 + wx * 8];
        float w0 = __expf(alast - ap[0]), w1 = __expf(alast - ap[1]);
        float w2 = __expf(alast - ap[2]), w3 = __expf(alast - ap[3]);
        float w4 = __expf(alast - ap[4]), w5 = __expf(alast - ap[5]);
        float w6 = __expf(alast - ap[6]), w7 = __expf(alast - ap[7]);
        s16x8 h8, l8;
        split8s(xp[0 * kDH] * w0, xp[1 * kDH] * w1, xp[2 * kDH] * w2, xp[3 * kDH] * w3,
                xp[4 * kDH] * w4, xp[5 * kDH] * w5, xp[6 * kDH] * w6, xp[7 * kDH] * w7,
                h8, l8);
        const int off = d * 32 + ((wx ^ ((d >> 2) & 3)) << 3);
        *(s16x8*)&XThi[off] = h8;
        *(s16x8*)&XTlo[off] = l8;
      }
      __syncthreads();
      const int aoff = st * 32 + ((fg ^ ((st >> 2) & 3)) << 3);
      s16x8 ah = *(const s16x8*)&BThi[aoff];
      s16x8 al = *(const s16x8*)&BTlo[aoff];
#pragma unroll
      for (int dg = 0; dg < 4; ++dg) {
        const int drow = dg * 16 + fr;
        const int xoff = drow * 32 + ((fg ^ ((drow >> 2) & 3)) << 3);
        s16x8 xh = *(const s16x8*)&XThi[xoff];
        s16x8 xl = *(const s16x8*)&XTlo[xoff];
        acc[dg] = __builtin_amdgcn_mfma_f32_16x16x32_bf16(ah, xh, acc[dg], 0, 0, 0);
        acc[dg] = __builtin_amdgcn_mfma_f32_16x16x32_bf16(ah, xl, acc[dg], 0, 0, 0);
        acc[dg] = __builtin_amdgcn_mfma_f32_16x16x32_bf16(al, xh, acc[dg], 0, 0, 0);
      }
      __syncthreads();
    }
    const float dscale = kAlpha * __expf(alast);
    const float sc = 1.f - kAlpha;
#pragma unroll
    for (int dg = 0; dg < 4; ++dg) {
#pragma unroll
      for (int r = 0; r < 4; ++r) {
        const int s = w * 16 + fg * 4 + r;
        const int d = dg * 16 + fr;
        Ob[(size_t)s * kDH + d] = dscale * Hb[(size_t)s * kDH + d] + sc * acc[dg][r];
      }
    }
    return;
  }

  // ======================= Y path (paired i-tiles) =======================
  const int itA = role;            // 0 or 1
  const int itB = 3 - role;        // 3 or 2
  const int i0A = itA * 64, i0B = itB * 64;
  const int jt_n = 2 * itB + 2;    // 8 or 6
  const int jtA_n = 2 * itA + 2;   // 2 or 4
  const bool gB = w >= 4;
  const int wl = w & 3;
  const int i0g = gB ? i0B : i0A;

  float* ac   = (float*)(smem + OFF_AC);
  float* eneg = (float*)(smem + OFF_ENEG);
  short* Bhi  = (short*)(smem + OFF_B);
  short* Blo  = (short*)(smem + OFF_BLO);
  short* XThi = (short*)(smem + OFF_XT);
  short* XTlo = (short*)(smem + OFF_XTLO);
  short* Sall = (short*)(smem + OFF_S);
  float* CbA  = (float*)(smem + OFF_B);   // fp32 bounce tile A (aliases B planes)
  float* CbB  = (float*)(smem + OFF_XT);  // fp32 bounce tile B (aliases XT+S)
  short* HThi = (short*)(smem + OFF_B);   // full [64][128] h_prev^T hi (16KB)
  short* HTlo = (short*)(smem + OFF_XT);  // full lo (16KB)

  const float* Cg_b = Cg + (size_t)bh * kCS * kDS;
  float* Yb = Yg + (size_t)bh * kCS * kDH;

  // ---- cumsum via wave shuffle scan (waves 0-3)
  {
    float v = 0.f;
    if (tid < 256) {
      v = Ab[tid];
#pragma unroll
      for (int off = 1; off < 64; off <<= 1) {
        float t = __shfl_up(v, off);
        if (lane >= off) v += t;
      }
      float* wsum = (float*)(smem + OFF_S);
      if (lane == 63) wsum[w] = v;
    }
    __syncthreads();
    if (tid < 256) {
      const float* wsum = (const float*)(smem + OFF_S);
      float base = 0.f;
#pragma unroll
      for (int k = 0; k < 4; ++k)
        if (k < w) base += wsum[k];
      const float a = v + base;
      ac[tid] = a;
      eneg[tid] = __expf(-a);
    }
    __syncthreads();
  }

  float eaci[4];
#pragma unroll
  for (int r = 0; r < 4; ++r) eaci[r] = __expf(ac[i0g + wl * 16 + fg * 4 + r]);

  // ---- issue jt=0 prefetch early (hides under C bounce). Threads 0-255: B;
  // threads 256-511: X.
  const int prow = (tid >> 4) & 15;
  const int pg = tid & 15;
  const int xd = (tid - 256) & 63;
  const int xw = ((tid - 256) >> 6) & 3;
  float4 pb0, pb1, pb2, pb3;
  float px0, px1, px2, px3, px4, px5, px6, px7;
  if (tid < 256) {
    pb0 = *(const float4*)&Bb[(size_t)prow * kDS + pg * 8];
    pb1 = *(const float4*)&Bb[(size_t)prow * kDS + pg * 8 + 4];
    pb2 = *(const float4*)&Bb[(size_t)(16 + prow) * kDS + pg * 8];
    pb3 = *(const float4*)&Bb[(size_t)(16 + prow) * kDS + pg * 8 + 4];
  } else {
    const float* xp = &Xb[(size_t)(xw * 8) * kDH + xd];
    px0 = xp[0 * kDH]; px1 = xp[1 * kDH]; px2 = xp[2 * kDH]; px3 = xp[3 * kDH];
    px4 = xp[4 * kDH]; px5 = xp[5 * kDH]; px6 = xp[6 * kDH]; px7 = xp[7 * kDH];
  }

  // ---- C bounce: both i-tiles in parallel, two 32-row halves each
  s16x8 chi[4], clo[4];
#pragma unroll
  for (int m = 0; m < 2; ++m) {
#pragma unroll
    for (int k = 0; k < 2; ++k) {
      int fid = k * 512 + tid;
      int r = fid >> 5, c = fid & 31;
      *(float4*)&CbA[r * 128 + ((c ^ (r & 7)) << 2)] =
          *(const float4*)&Cg_b[(size_t)(i0A + m * 32 + r) * kDS + c * 4];
      *(float4*)&CbB[r * 128 + ((c ^ (r & 7)) << 2)] =
          *(const float4*)&Cg_b[(size_t)(i0B + m * 32 + r) * kDS + c * 4];
    }
    __syncthreads();
    if ((wl >> 1) == m) {
      const int lrow = (wl & 1) * 16 + fr;
      const float* crow = (gB ? CbB : CbA) + lrow * 128;
      const int r7 = lrow & 7;
#pragma unroll
      for (int kc = 0; kc < 4; ++kc) {
        const int c0 = kc * 8 + fg * 2;
        F4 u0, u1;
        u0.v = *(const float4*)&crow[(c0 ^ r7) << 2];
        u1.v = *(const float4*)&crow[((c0 + 1) ^ r7) << 2];
        split8v(u0.v, u1.v, chi[kc], clo[kc]);
      }
    }
    __syncthreads();
  }

  f32x4 yacc[4];
#pragma unroll
  for (int n = 0; n < 4; ++n)
#pragma unroll
    for (int r = 0; r < 4; ++r) yacc[n][r] = 0.f;

  short* Sp = Sall + w * 512;  // per-wave S~ plane [16][32]

  for (int jt = 0; jt < jt_n; ++jt) {
    // ---- split+write current tile from named prefetch regs
    if (tid < 256) {
      s16x8 h8, l8;
      split8v(pb0, pb1, h8, l8);
      int col = (pg ^ (prow & 7)) * 8;
      *(s16x8*)&Bhi[prow * 128 + col] = h8;
      *(s16x8*)&Blo[prow * 128 + col] = l8;
      const int row1 = 16 + prow;
      split8v(pb2, pb3, h8, l8);
      col = (pg ^ (row1 & 7)) * 8;
      *(s16x8*)&Bhi[row1 * 128 + col] = h8;
      *(s16x8*)&Blo[row1 * 128 + col] = l8;
    } else {
      s16x8 h8, l8;
      split8s(px0, px1, px2, px3, px4, px5, px6, px7, h8, l8);
      const int off = xd * 32 + ((xw ^ ((xd >> 2) & 3)) << 3);
      *(s16x8*)&XThi[off] = h8;
      *(s16x8*)&XTlo[off] = l8;
    }
    // ---- issue next tile's loads; stay in flight across both lds_barriers
    if (jt + 1 < jt_n) {
      const int j0n = (jt + 1) * 32;
      if (tid < 256) {
        pb0 = *(const float4*)&Bb[(size_t)(j0n + prow) * kDS + pg * 8];
        pb1 = *(const float4*)&Bb[(size_t)(j0n + prow) * kDS + pg * 8 + 4];
        pb2 = *(const float4*)&Bb[(size_t)(j0n + 16 + prow) * kDS + pg * 8];
        pb3 = *(const float4*)&Bb[(size_t)(j0n + 16 + prow) * kDS + pg * 8 + 4];
      } else {
        const float* xp = &Xb[(size_t)(j0n + xw * 8) * kDH + xd];
        px0 = xp[0 * kDH]; px1 = xp[1 * kDH]; px2 = xp[2 * kDH]; px3 = xp[3 * kDH];
        px4 = xp[4 * kDH]; px5 = xp[5 * kDH]; px6 = xp[6 * kDH]; px7 = xp[7 * kDH];
      }
    }
    lds_barrier();

    // group A computes only while jt within its causal span; group B always
    if (gB || jt < jtA_n) {
      const int j0 = jt * 32;
      // ---- S = C·B^T, split hi/lo, split accumulator chains
      f32x4 sA[2], sB[2];
#pragma unroll
      for (int n = 0; n < 2; ++n) {
#pragma unroll
        for (int r = 0; r < 4; ++r) { sA[n][r] = 0.f; sB[n][r] = 0.f; }
        const int jrow = n * 16 + fr;
        const short* bph = &Bhi[jrow * 128];
        const short* bpl = &Blo[jrow * 128];
#pragma unroll
        for (int kc = 0; kc < 2; ++kc) {
          const int phys = ((4 * kc + fg) ^ (jrow & 7)) * 8;
          s16x8 b8 = *(const s16x8*)&bph[phys];
          s16x8 l8 = *(const s16x8*)&bpl[phys];
          sA[n] = __builtin_amdgcn_mfma_f32_16x16x32_bf16(chi[kc], b8, sA[n], 0, 0, 0);
          sA[n] = __builtin_amdgcn_mfma_f32_16x16x32_bf16(chi[kc], l8, sA[n], 0, 0, 0);
          sA[n] = __builtin_amdgcn_mfma_f32_16x16x32_bf16(clo[kc], b8, sA[n], 0, 0, 0);
        }
#pragma unroll
        for (int kc = 2; kc < 4; ++kc) {
          const int phys = ((4 * kc + fg) ^ (jrow & 7)) * 8;
          s16x8 b8 = *(const s16x8*)&bph[phys];
          s16x8 l8 = *(const s16x8*)&bpl[phys];
          sB[n] = __builtin_amdgcn_mfma_f32_16x16x32_bf16(chi[kc], b8, sB[n], 0, 0, 0);
          sB[n] = __builtin_amdgcn_mfma_f32_16x16x32_bf16(chi[kc], l8, sB[n], 0, 0, 0);
          sB[n] = __builtin_amdgcn_mfma_f32_16x16x32_bf16(clo[kc], b8, sB[n], 0, 0, 0);
        }
      }
      // ---- mask + decay, write S~ (bf16 hi) to per-wave plane
#pragma unroll
      for (int n = 0; n < 2; ++n) {
        const int jg = j0 + n * 16 + fr;
        const float enj = eneg[jg];
#pragma unroll
        for (int r = 0; r < 4; ++r) {
          const int iwl = fg * 4 + r;
          const int ig = i0g + wl * 16 + iwl;
          float sv = (sA[n][r] + sB[n][r]) * eaci[r] * enj;
          sv = (jg <= ig) ? sv : 0.f;
          Sp[iwl * 32 + (((n * 2 + (fr >> 3)) ^ fg) << 3) + (fr & 7)] = (short)bf16_1(sv);
        }
      }
      // ---- PV: Y += S~ · X
      {
        s16x8 sa = *(const s16x8*)&Sp[fr * 32 + ((fg ^ (fr >> 2)) << 3)];
#pragma unroll
        for (int n = 0; n < 4; ++n) {
          const int drow = n * 16 + fr;
          const int pxo = (fg ^ ((drow >> 2) & 3)) << 3;
          s16x8 xh = *(const s16x8*)&XThi[drow * 32 + pxo];
          s16x8 xl = *(const s16x8*)&XTlo[drow * 32 + pxo];
          yacc[n] = __builtin_amdgcn_mfma_f32_16x16x32_bf16(sa, xh, yacc[n], 0, 0, 0);
          yacc[n] = __builtin_amdgcn_mfma_f32_16x16x32_bf16(sa, xl, yacc[n], 0, 0, 0);
        }
      }
    }
    lds_barrier();
  }

  // ---- Yh = C · h_prev: full h_prev^T staged once (512 thr), both groups MFMA
  {
    const int dd = tid & 15, tt = tid >> 4;  // tt 0..31 -> full 128 s
    F4 hr[4];
#pragma unroll
    for (int r = 0; r < 4; ++r)
      hr[r].v = *(const float4*)&Hb[(size_t)(tt * 4 + r) * kDH + dd * 4];
#pragma unroll
    for (int c = 0; c < 4; ++c) {
      const int d = dd * 4 + c;
      unsigned h0, h1, l0, l1;
      split2(hr[0].f[c], hr[1].f[c], h0, l0);
      split2(hr[2].f[c], hr[3].f[c], h1, l1);
      const int off = d * 128 + (((tt >> 1) ^ (d & 7)) << 3) + ((tt & 1) << 2);
      ((unsigned*)&HThi[off])[0] = h0;
      ((unsigned*)&HThi[off])[1] = h1;
      ((unsigned*)&HTlo[off])[0] = l0;
      ((unsigned*)&HTlo[off])[1] = l1;
    }
  }
  __syncthreads();

  f32x4 yh[4];
#pragma unroll
  for (int n = 0; n < 4; ++n)
#pragma unroll
    for (int r = 0; r < 4; ++r) yh[n][r] = 0.f;

#pragma unroll
  for (int kc = 0; kc < 4; ++kc) {
#pragma unroll
    for (int n = 0; n < 4; ++n) {
      const int drow = n * 16 + fr;
      const int phys = ((4 * kc + fg) ^ (drow & 7)) * 8;
      s16x8 hh = *(const s16x8*)&HThi[drow * 128 + phys];
      s16x8 hl = *(const s16x8*)&HTlo[drow * 128 + phys];
      yh[n] = __builtin_amdgcn_mfma_f32_16x16x32_bf16(chi[kc], hh, yh[n], 0, 0, 0);
      yh[n] = __builtin_amdgcn_mfma_f32_16x16x32_bf16(chi[kc], hl, yh[n], 0, 0, 0);
      yh[n] = __builtin_amdgcn_mfma_f32_16x16x32_bf16(clo[kc], hh, yh[n], 0, 0, 0);
    }
  }

  // ---- epilogue: Y = (1-a)*Y_intra + a*exp(ac_i)*Yh
#pragma unroll
  for (int n = 0; n < 4; ++n) {
#pragma unroll
    for (int r = 0; r < 4; ++r) {
      const int ig = i0g + wl * 16 + fg * 4 + r;
      const int d = n * 16 + fr;
      Yb[(size_t)ig * kDH + d] = (1.f - kAlpha) * yacc[n][r] + (kAlpha * eaci[r]) * yh[n][r];
    }
  }
}

extern "C" void kernel_launch(void* const* d_in, const int* in_sizes, int n_in,
                              void* d_out, int out_size, void* d_ws, size_t ws_size,
                              hipStream_t stream) {
  const float* X = (const float*)d_in[0];
  const float* A = (const float*)d_in[1];
  const float* B = (const float*)d_in[2];
  const float* C = (const float*)d_in[3];
  const float* H = (const float*)d_in[4];
  float* out = (float*)d_out;
  float* Y = out;
  float* hend = Y + (size_t)kBH * kCS * kDH;
  float* dt = hend + (size_t)kBH * kDS * kDH;

  fused_kernel<<<1536, 512, 0, stream>>>(X, A, B, C, H, Y, hend, dt);
}